// Round 14
// baseline (283.071 us; speedup 1.0000x reference)
//
#include <hip/hip_runtime.h>
#include <hip/hip_bf16.h>
#include <cmath>

typedef long long i64;
typedef unsigned short u16;
typedef __attribute__((ext_vector_type(8))) short short8;
typedef __attribute__((ext_vector_type(8))) unsigned short u16x8;
typedef __attribute__((ext_vector_type(4))) float f32x4;
typedef __attribute__((ext_vector_type(4))) int i32x4;

#define NB 4
#define NL 1024
#define ND 512
#define NH 8

__device__ __forceinline__ u16 f2bf(float f) {
    __hip_bfloat16 h = __float2bfloat16(f);
    return __builtin_bit_cast(unsigned short, h);
}
__device__ __forceinline__ float bf2f(u16 u) {
    return __builtin_bit_cast(float, (unsigned)u << 16);
}

// async global->LDS, 16B per lane. LDS dest is wave-uniform base + lane*16.
typedef __attribute__((address_space(3))) u16* lds_u16p;
typedef const __attribute__((address_space(1))) u16* glb_u16p;
__device__ __forceinline__ void gl_lds16(const u16* g, u16* l) {
    __builtin_amdgcn_global_load_lds((glb_u16p)g, (lds_u16p)l, 16, 0, 0);
}

// ---------------------------------------------------------------------------
// fused fp32 -> bf16 convert for up to 4 tensors (blockIdx.y selects)
// ---------------------------------------------------------------------------
struct CvtArgs {
    const float* src[4];
    u16* dst[4];
};

__global__ __launch_bounds__(256) void cvt_multi_kernel(CvtArgs args, int n8)
{
    int i = blockIdx.x * 256 + threadIdx.x;
    if (i >= n8) return;
    const float* __restrict__ src = args.src[blockIdx.y];
    u16* __restrict__ dst = args.dst[blockIdx.y];
    float4 a = ((const float4*)src)[2 * i];
    float4 b = ((const float4*)src)[2 * i + 1];
    u16x8 o;
    o[0] = f2bf(a.x); o[1] = f2bf(a.y); o[2] = f2bf(a.z); o[3] = f2bf(a.w);
    o[4] = f2bf(b.x); o[5] = f2bf(b.y); o[6] = f2bf(b.z); o[7] = f2bf(b.w);
    *(u16x8*)&dst[8 * i] = o;
}

// ---------------------------------------------------------------------------
// bf16 MFMA GEMM, BT-form:  C[m,n] = alpha * sum_k A[m,k]*B[n,k]  (+ bias[n])
// A: [M,K] bf16 (lda), B: [N,K] bf16 (ldb), C: fp32 or bf16 (OUTBF, ldc).
// z-offsets (div fixed at 8):  off = (z>>3)*s1 + (z&7)*s2  for A, B, C.
// m97 geometry, BK=32 DOUBLE-BUFFERED (32 KB LDS -> ~5 blocks/CU), T2
// XOR-swizzle, T1 XCD-chunked block swizzle, T3/T4 counted vmcnt(4):
// next tile's 4 global_load_lds stay in flight across both raw s_barriers.
// LDS[r][chunk p] = G[r][p ^ (r&3)] (16B chunks) via pre-swizzled source;
// read applies kblk ^ (lrow&3) -> b128-minimum bank schedule.
// M,N multiples of 128; K multiple of 32; lda/ldb multiples of 8.
// ---------------------------------------------------------------------------
template <bool OUTBF, bool BIAS>
__global__ __launch_bounds__(256) void mfma_gemm(
    const u16* __restrict__ A, const u16* __restrict__ B,
    void* __restrict__ Cv, const float* __restrict__ bias,
    int K, int lda, int ldb, int ldc, float alpha,
    i64 a_s1, i64 a_s2, i64 b_s1, i64 b_s2, i64 c_s1, i64 c_s2)
{
    // ---- XCD-chunked swizzle: contiguous work chunk per XCD (L2 locality)
    const int gxy  = gridDim.x * gridDim.y;
    const int nblk = gxy * gridDim.z;
    const int lin  = blockIdx.x + gridDim.x * blockIdx.y + gxy * blockIdx.z;
    const int swz  = (lin & 7) * (nblk >> 3) + (lin >> 3);
    const int bz   = swz / gxy;
    const int rxy  = swz - bz * gxy;
    const int by   = rxy / gridDim.x;
    const int bx   = rxy - by * gridDim.x;

    const int zh = bz >> 3, zl = bz & 7;
    A += (i64)zh * a_s1 + (i64)zl * a_s2;
    B += (i64)zh * b_s1 + (i64)zl * b_s2;
    const i64 coff = (i64)zh * c_s1 + (i64)zl * c_s2;

    __shared__ alignas(16) u16 As[2 * 128 * 32];   // 2 x 8 KB
    __shared__ alignas(16) u16 Bs[2 * 128 * 32];

    const int tid  = threadIdx.x;
    const int lane = tid & 63;
    const int wave = tid >> 6;           // 0..3
    const int wr   = (wave >> 1) * 64;   // wave row offset: 0,64
    const int wc   = (wave & 1) * 64;    // wave col offset: 0,64
    const int lrow = lane & 15;
    const int kblk = lane >> 4;          // 0..3
    const int rchk = (kblk ^ (lrow & 3)) << 3;  // read chunk (u16 units)
    const int m0   = by * 128;
    const int n0   = bx * 128;

    // staging: wave w stages rows [32w,32w+32); 2 issues of 16 rows per
    // operand. lane l -> rel row (l>>2), source chunk ((l&3) ^ ((l>>2)&3)).
    const int srow0 = wave * 32;
    const int grow  = srow0 + (lane >> 2);
    const int gchk  = (((lane & 3) ^ ((lane >> 2) & 3))) * 8;

    f32x4 acc[4][4];
    #pragma unroll
    for (int i = 0; i < 4; ++i)
        #pragma unroll
        for (int j = 0; j < 4; ++j)
            acc[i][j] = (f32x4){0.f, 0.f, 0.f, 0.f};

    const int nt = K >> 5;   // K / 32 tiles

    // prologue: stage tile 0 into buffer 0 (2 issues A + 2 issues B)
    #pragma unroll
    for (int j = 0; j < 2; ++j)
        gl_lds16(&A[(i64)(m0 + grow + 16 * j) * lda + gchk],
                 &As[(srow0 + 16 * j) * 32]);
    #pragma unroll
    for (int j = 0; j < 2; ++j)
        gl_lds16(&B[(i64)(n0 + grow + 16 * j) * ldb + gchk],
                 &Bs[(srow0 + 16 * j) * 32]);

    int cur = 0;
    for (int t = 0; t < nt; ++t) {
        const int nxt = cur ^ 1;
        if (t + 1 < nt) {
            const int k0n = (t + 1) << 5;
            #pragma unroll
            for (int j = 0; j < 2; ++j)
                gl_lds16(&A[(i64)(m0 + grow + 16 * j) * lda + k0n + gchk],
                         &As[nxt * 4096 + (srow0 + 16 * j) * 32]);
            #pragma unroll
            for (int j = 0; j < 2; ++j)
                gl_lds16(&B[(i64)(n0 + grow + 16 * j) * ldb + k0n + gchk],
                         &Bs[nxt * 4096 + (srow0 + 16 * j) * 32]);
            // wait only for the OLDEST 4 (current tile); prefetch in flight
            asm volatile("s_waitcnt vmcnt(4)" ::: "memory");
        } else {
            asm volatile("s_waitcnt vmcnt(0)" ::: "memory");
        }
        asm volatile("s_barrier" ::: "memory");   // buf[cur] ready on all waves

        const u16* Ab = &As[cur * 4096];
        const u16* Bb = &Bs[cur * 4096];
        short8 af[4], bg[4];
        #pragma unroll
        for (int m = 0; m < 4; ++m)
            af[m] = *(const short8*)&Ab[(wr + m * 16 + lrow) * 32 + rchk];
        #pragma unroll
        for (int n = 0; n < 4; ++n)
            bg[n] = *(const short8*)&Bb[(wc + n * 16 + lrow) * 32 + rchk];

        #pragma unroll
        for (int m = 0; m < 4; ++m)
            #pragma unroll
            for (int n = 0; n < 4; ++n)
                acc[m][n] = __builtin_amdgcn_mfma_f32_16x16x32_bf16(
                    af[m], bg[n], acc[m][n], 0, 0, 0);

        asm volatile("s_barrier" ::: "memory");   // all reads of buf[cur] done
        cur = nxt;
    }

    // epilogue: C/D layout col = lane&15, row = 4*(lane>>4)+reg
    #pragma unroll
    for (int m = 0; m < 4; ++m) {
        #pragma unroll
        for (int n = 0; n < 4; ++n) {
            const int col = n0 + wc + n * 16 + lrow;
            float bv = BIAS ? bias[col] : 0.f;
            #pragma unroll
            for (int r = 0; r < 4; ++r) {
                const int row = m0 + wr + m * 16 + kblk * 4 + r;
                float val = acc[m][n][r] * alpha + bv;
                if (OUTBF)
                    ((u16*)Cv)[coff + (i64)row * ldc + col] = f2bf(val);
                else
                    ((float*)Cv)[coff + (i64)row * ldc + col] = val;
            }
        }
    }
}

// ---------------------------------------------------------------------------
// split-K reduce + bias: out[i] = sum_p part[p*pstride + i] + bias[i % ND]
// ---------------------------------------------------------------------------
template <int P>
__global__ __launch_bounds__(256) void reduce_fc_kernel(
    const float* __restrict__ part, const float* __restrict__ bias,
    float* __restrict__ outp, i64 pstride)
{
    i64 idx = (i64)blockIdx.x * 256 + threadIdx.x;
    float s = bias[idx & (ND - 1)];
    #pragma unroll
    for (int p = 0; p < P; ++p) s += part[(i64)p * pstride + idx];
    outp[idx] = s;
}

// ---------------------------------------------------------------------------
__device__ __forceinline__ float wave_red_sum(float v) {
    #pragma unroll
    for (int o = 32; o > 0; o >>= 1) v += __shfl_down(v, o, 64);
    return v;
}

// ---------------------------------------------------------------------------
// Barrier-free fused masked softmax + renorm + head-mean.
// Wave w handles heads {w, w+4} of one (batch, q-row); full-row reductions
// via 6-step shfl_xor butterflies (no __syncthreads in head loop).
// ---------------------------------------------------------------------------
__global__ __launch_bounds__(256) void softmax_fused_kernel(
    const u16* __restrict__ scores, const int* __restrict__ mask,
    u16* __restrict__ attn_bf, float* __restrict__ amean,
    i64 s_bstride, i64 m_bstride, i64 a_bstride, i64 o_bstride)
{
    const int qrow = blockIdx.x;
    const int bb   = blockIdx.y;
    const u16* sbase = scores + (i64)bb * s_bstride;
    const int* mrow = mask + (i64)bb * m_bstride + (i64)qrow * NL;
    u16* abase = attn_bf + (i64)bb * a_bstride;
    float* orow = amean + (i64)bb * o_bstride + (i64)qrow * NL;

    const int tid  = threadIdx.x;
    const int lane = tid & 63;
    const int wave = tid >> 6;           // 0..3

    __shared__ float wsum[4][NL];        // per-wave head-sum partials

    const int e0 = lane * 8;
    const int e1 = 512 + lane * 8;

    float mv[16];
    {
        i32x4 m0a = *(const i32x4*)&mrow[e0];
        i32x4 m0b = *(const i32x4*)&mrow[e0 + 4];
        i32x4 m1a = *(const i32x4*)&mrow[e1];
        i32x4 m1b = *(const i32x4*)&mrow[e1 + 4];
        #pragma unroll
        for (int i = 0; i < 4; ++i) {
            mv[i]      = (float)m0a[i];
            mv[4 + i]  = (float)m0b[i];
            mv[8 + i]  = (float)m1a[i];
            mv[12 + i] = (float)m1b[i];
        }
    }

    float msum[16];
    #pragma unroll
    for (int i = 0; i < 16; ++i) msum[i] = 0.f;

    #pragma unroll
    for (int hh = 0; hh < 2; ++hh) {
        const int h = wave + hh * 4;
        const u16* srow_p = sbase + ((i64)h * NL + qrow) * NL;
        u16* arow_p = abase + ((i64)h * NL + qrow) * NL;

        u16x8 s0 = *(const u16x8*)&srow_p[e0];
        u16x8 s1 = *(const u16x8*)&srow_p[e1];

        float zv[16];
        float lmax = -1e30f;
        #pragma unroll
        for (int i = 0; i < 8; ++i) {
            zv[i]     = bf2f(s0[i]) * mv[i];
            zv[8 + i] = bf2f(s1[i]) * mv[8 + i];
        }
        #pragma unroll
        for (int i = 0; i < 16; ++i) lmax = fmaxf(lmax, zv[i]);
        #pragma unroll
        for (int o = 1; o < 64; o <<= 1)
            lmax = fmaxf(lmax, __shfl_xor(lmax, o, 64));

        float e[16];
        float ls = 0.f;
        #pragma unroll
        for (int i = 0; i < 16; ++i) { e[i] = __expf(zv[i] - lmax); ls += e[i]; }
        #pragma unroll
        for (int o = 1; o < 64; o <<= 1) ls += __shfl_xor(ls, o, 64);

        float ls2 = 0.f;
        #pragma unroll
        for (int i = 0; i < 16; ++i) { e[i] = e[i] / ls * mv[i]; ls2 += e[i]; }
        #pragma unroll
        for (int o = 1; o < 64; o <<= 1) ls2 += __shfl_xor(ls2, o, 64);

        const float inv = 1.0f / (ls2 + 1e-13f);
        u16x8 o0, o1;
        #pragma unroll
        for (int i = 0; i < 8; ++i) {
            float p0 = e[i] * inv;
            float p1 = e[8 + i] * inv;
            o0[i] = f2bf(p0);
            o1[i] = f2bf(p1);
            msum[i]     += p0;
            msum[8 + i] += p1;
        }
        *(u16x8*)&arow_p[e0] = o0;
        *(u16x8*)&arow_p[e1] = o1;
    }

    #pragma unroll
    for (int i = 0; i < 8; ++i) {
        wsum[wave][e0 + i] = msum[i];
        wsum[wave][e1 + i] = msum[8 + i];
    }
    __syncthreads();
    #pragma unroll
    for (int i = 0; i < 4; ++i) {
        int j = tid + i * 256;
        orow[j] = (wsum[0][j] + wsum[1][j] + wsum[2][j] + wsum[3][j]) * 0.125f;
    }
}

// ---------------------------------------------------------------------------
// residual add + LayerNorm over D=512. grid: rows, 256 threads (2 elem/thr)
// ---------------------------------------------------------------------------
__global__ __launch_bounds__(256) void ln_kernel(
    const float* __restrict__ fcout, const float* __restrict__ resid,
    const float* __restrict__ gamma, const float* __restrict__ beta,
    float* __restrict__ out)
{
    const int row = blockIdx.x;
    const float* xr = fcout + (i64)row * ND;
    const float* rr = resid + (i64)row * ND;
    const int tid = threadIdx.x;
    const int lane = tid & 63, wid = tid >> 6;
    __shared__ float red[8];

    float x0 = xr[tid] + rr[tid];
    float x1 = xr[tid + 256] + rr[tid + 256];
    float s  = x0 + x1;
    float s2 = x0 * x0 + x1 * x1;
    s  = wave_red_sum(s);
    s2 = wave_red_sum(s2);
    if (lane == 0) { red[wid] = s; red[4 + wid] = s2; }
    __syncthreads();
    const float S  = red[0] + red[1] + red[2] + red[3];
    const float S2 = red[4] + red[5] + red[6] + red[7];
    const float mu  = S * (1.0f / ND);
    const float var = S2 * (1.0f / ND) - mu * mu;
    const float inv = rsqrtf(var + 1e-5f);

    out[(i64)row * ND + tid]       = (x0 - mu) * inv * gamma[tid] + beta[tid];
    out[(i64)row * ND + tid + 256] = (x1 - mu) * inv * gamma[tid + 256] + beta[tid + 256];
}

// ===========================================================================
// Fallback fp32 path (small workspace): per-(b,h) scalar GEMM pipeline.
// ===========================================================================
template <bool BT, bool BIAS, bool ACC>
__global__ __launch_bounds__(256) void gemm_kernel(
    const float* __restrict__ A, const float* __restrict__ B,
    float* __restrict__ C, const float* __restrict__ bias,
    int M, int N, int K, int lda, int ldb, int ldc, float alpha)
{
    __shared__ float Asf[16][68];
    __shared__ float Bsf[16][68];
    const int tid = threadIdx.x;
    const int tx = tid & 15, ty = tid >> 4;
    const int m0 = blockIdx.y * 64, n0 = blockIdx.x * 64;
    float acc[4][4] = {};

    for (int k0 = 0; k0 < K; k0 += 16) {
        {
            int r = tid >> 2, kq = (tid & 3) << 2;
            float4 a = *reinterpret_cast<const float4*>(&A[(i64)(m0 + r) * lda + k0 + kq]);
            Asf[kq][r] = a.x; Asf[kq + 1][r] = a.y; Asf[kq + 2][r] = a.z; Asf[kq + 3][r] = a.w;
        }
        if (BT) {
            int r = tid >> 2, kq = (tid & 3) << 2;
            float4 b = *reinterpret_cast<const float4*>(&B[(i64)(n0 + r) * ldb + k0 + kq]);
            Bsf[kq][r] = b.x; Bsf[kq + 1][r] = b.y; Bsf[kq + 2][r] = b.z; Bsf[kq + 3][r] = b.w;
        } else {
            int kk = tid >> 4, n4 = (tid & 15) << 2;
            float4 b = *reinterpret_cast<const float4*>(&B[(i64)(k0 + kk) * ldb + n0 + n4]);
            *reinterpret_cast<float4*>(&Bsf[kk][n4]) = b;
        }
        __syncthreads();
        #pragma unroll
        for (int kk = 0; kk < 16; ++kk) {
            float4 a4 = *reinterpret_cast<const float4*>(&Asf[kk][ty << 2]);
            float4 b4 = *reinterpret_cast<const float4*>(&Bsf[kk][tx << 2]);
            float a[4] = {a4.x, a4.y, a4.z, a4.w};
            float b[4] = {b4.x, b4.y, b4.z, b4.w};
            #pragma unroll
            for (int i = 0; i < 4; ++i)
                #pragma unroll
                for (int j = 0; j < 4; ++j)
                    acc[i][j] = fmaf(a[i], b[j], acc[i][j]);
        }
        __syncthreads();
    }
    #pragma unroll
    for (int i = 0; i < 4; ++i) {
        int m = m0 + (ty << 2) + i;
        #pragma unroll
        for (int j = 0; j < 4; ++j) {
            int n = n0 + (tx << 2) + j;
            float val = acc[i][j] * alpha;
            if (BIAS) val += bias[n];
            i64 idx = (i64)m * ldc + n;
            if (ACC) C[idx] += val; else C[idx] = val;
        }
    }
}

__device__ __forceinline__ float wave_red_max(float v) {
    #pragma unroll
    for (int o = 32; o > 0; o >>= 1) v = fmaxf(v, __shfl_down(v, o, 64));
    return v;
}

__global__ __launch_bounds__(256) void softmax_kernel(
    float* __restrict__ attn, const int* __restrict__ mask)
{
    const int qrow = blockIdx.x;
    float* row = attn + (i64)qrow * NL;
    const int* mrow = mask + (i64)qrow * NL;
    const int tid = threadIdx.x;
    const int lane = tid & 63, wid = tid >> 6;
    __shared__ float red[4];

    float zv[4], mv[4];
    float lmax = -1e30f;
    #pragma unroll
    for (int i = 0; i < 4; ++i) {
        mv[i] = (float)mrow[tid + i * 256];
        zv[i] = row[tid + i * 256] * mv[i];
        lmax  = fmaxf(lmax, zv[i]);
    }
    float wv = wave_red_max(lmax);
    if (lane == 0) red[wid] = wv;
    __syncthreads();
    const float gmax = fmaxf(fmaxf(red[0], red[1]), fmaxf(red[2], red[3]));
    float e[4]; float ls = 0.f;
    #pragma unroll
    for (int i = 0; i < 4; ++i) { e[i] = __expf(zv[i] - gmax); ls += e[i]; }
    __syncthreads();
    wv = wave_red_sum(ls);
    if (lane == 0) red[wid] = wv;
    __syncthreads();
    const float S1 = red[0] + red[1] + red[2] + red[3];
    float ls2 = 0.f;
    #pragma unroll
    for (int i = 0; i < 4; ++i) { e[i] = e[i] / S1 * mv[i]; ls2 += e[i]; }
    __syncthreads();
    wv = wave_red_sum(ls2);
    if (lane == 0) red[wid] = wv;
    __syncthreads();
    const float S2 = red[0] + red[1] + red[2] + red[3];
    const float inv = 1.0f / (S2 + 1e-13f);
    #pragma unroll
    for (int i = 0; i < 4; ++i) row[tid + i * 256] = e[i] * inv;
}

__global__ __launch_bounds__(256) void mean_acc_kernel(
    const float* __restrict__ attn, float* __restrict__ out, int first)
{
    i64 idx = (i64)blockIdx.x * 256 + threadIdx.x;
    float v = attn[idx] * 0.125f;
    out[idx] = first ? v : (out[idx] + v);
}

// ---------------------------------------------------------------------------
extern "C" void kernel_launch(void* const* d_in, const int* in_sizes, int n_in,
                              void* d_out, int out_size, void* d_ws, size_t ws_size,
                              hipStream_t stream)
{
    const float* q     = (const float*)d_in[0];
    const int*   mask  = (const int*)  d_in[1];
    const float* k     = (const float*)d_in[2];
    const float* v     = (const float*)d_in[3];
    const float* Wq    = (const float*)d_in[4];
    const float* Wk    = (const float*)d_in[5];
    const float* Wv    = (const float*)d_in[6];
    const float* Wfc   = (const float*)d_in[7];
    const float* bfc   = (const float*)d_in[8];
    const float* gamma = (const float*)d_in[9];
    const float* beta  = (const float*)d_in[10];

    float* out       = (float*)d_out;                 // [B,L,D]
    float* attn_mean = out + (i64)NB * NL * ND;       // [B,L,L]

    const float inv_sqrt_d = 0.04419417382415922f;    // 1/sqrt(512)
    const i64 LD  = (i64)NL * ND;                     // 524288
    const i64 LL  = (i64)NL * NL;                     // 1048576
    const i64 ND2 = (i64)ND * ND;                     // 262144
    const i64 HLD = (i64)NH * LD;                     // 4194304
    const i64 HLL = (i64)NH * LL;                     // 8388608
    dim3 blk(256);

    const size_t MB = 1048576;

    if (ws_size >= 196 * MB) {
        // ================= full-batch bf16 MFMA path (196 MiB) =================
        char* wsb = (char*)d_ws;
        u16* Wq_bf  = (u16*)(wsb);              // 4 MiB each
        u16* Wk_bf  = (u16*)(wsb + 4   * MB);
        u16* Wv_bf  = (u16*)(wsb + 8   * MB);
        u16* Wfc_bf = (u16*)(wsb + 12  * MB);
        u16* q_bf   = (u16*)(wsb + 16  * MB);   // [B,L,D] bf16, 4 MiB each
        u16* k_bf   = (u16*)(wsb + 20  * MB);
        u16* v_bf   = (u16*)(wsb + 24  * MB);
        u16* qh     = (u16*)(wsb + 28  * MB);   // [B,H,L,D] bf16, 32 MiB
        u16* kh     = (u16*)(wsb + 60  * MB);   // [B,H,L,D] bf16, 32 MiB
        u16* vht    = (u16*)(wsb + 92  * MB);   // [B,H,D,L] bf16, 32 MiB
        u16* scores = (u16*)(wsb + 124 * MB);   // [B,H,L,L] bf16, 64 MiB -> 188
        u16* attn_bf  = qh;                      // [B,H,L,L] bf16, over qh+kh
        u16* concat   = (u16*)(wsb + 124 * MB);  // [B*L,H*D] bf16, 32 MiB (scores dead)
        float* fcpart = (float*)(wsb + 156 * MB);// [4, B*L, 512] f32, 32 MiB
        float* fcout  = (float*)(wsb + 188 * MB);// [B*L, 512] f32, 8 MiB -> 196

        // ---- all weights -> bf16 (one launch)
        {
            CvtArgs a;
            a.src[0] = Wq;  a.dst[0] = Wq_bf;
            a.src[1] = Wk;  a.dst[1] = Wk_bf;
            a.src[2] = Wv;  a.dst[2] = Wv_bf;
            a.src[3] = Wfc; a.dst[3] = Wfc_bf;
            cvt_multi_kernel<<<dim3(1024, 4), blk, 0, stream>>>(a, 262144);
        }
        // ---- all inputs -> bf16 (one launch)
        {
            CvtArgs a;
            a.src[0] = q; a.dst[0] = q_bf;
            a.src[1] = k; a.dst[1] = k_bf;
            a.src[2] = v; a.dst[2] = v_bf;
            a.src[3] = q; a.dst[3] = q_bf;     // unused (y<3)
            cvt_multi_kernel<<<dim3(1024, 3), blk, 0, stream>>>(a, 262144);
        }

        // ---- projections, z = b*8+h (32)
        mfma_gemm<true, false><<<dim3(4, 8, 32), blk, 0, stream>>>(
            q_bf, Wq_bf, qh, nullptr, ND, ND, ND, ND, 1.0f,
            LD, 0, 0, ND2, HLD, LD);
        mfma_gemm<true, false><<<dim3(4, 8, 32), blk, 0, stream>>>(
            k_bf, Wk_bf, kh, nullptr, ND, ND, ND, ND, 1.0f,
            LD, 0, 0, ND2, HLD, LD);
        mfma_gemm<true, false><<<dim3(8, 4, 32), blk, 0, stream>>>(
            Wv_bf, v_bf, vht, nullptr, ND, ND, ND, NL, 1.0f,
            0, ND2, LD, 0, HLD, LD);

        // ---- scores[b,h,q,k] = (1/sqrt(D)) qh . kh  -> bf16
        mfma_gemm<true, false><<<dim3(8, 8, 32), blk, 0, stream>>>(
            qh, kh, scores, nullptr, ND, ND, ND, NL, inv_sqrt_d,
            HLD, LD, HLD, LD, HLL, LL);

        // ---- softmax + renorm + bf16 attn + head-mean (all batches)
        softmax_fused_kernel<<<dim3(NL, NB), blk, 0, stream>>>(
            scores, mask, attn_bf, attn_mean, HLL, LL, HLL, LL);

        // ---- PV: concat[b*L+l, h*512+e] = sum_k attn[b,h,l,k] vht[b,h,e,k]
        mfma_gemm<true, false><<<dim3(4, 8, 32), blk, 0, stream>>>(
            attn_bf, vht, concat, nullptr, NL, NL, NL, NH * ND, 1.0f,
            HLL, LL, HLD, LD, (i64)NL * NH * ND, (i64)ND);

        // ---- fc split-K: z = K-chunk (4 x 1024)
        mfma_gemm<false, false><<<dim3(4, 32, 4), blk, 0, stream>>>(
            concat, Wfc_bf, fcpart, nullptr, NL, NH * ND, NH * ND, ND, 1.0f,
            0, NL, 0, NL, 0, (i64)NB * NL * ND);
        reduce_fc_kernel<4><<<dim3(8192), blk, 0, stream>>>(
            fcpart, bfc, fcout, (i64)NB * NL * ND);

        // ---- residual + LayerNorm (all batches)
        ln_kernel<<<dim3(NB * NL), blk, 0, stream>>>(fcout, q, gamma, beta, out);

    } else if (ws_size >= 64 * MB) {
        // ================= per-batch bf16 MFMA path (61 MiB) =================
        char* wsb = (char*)d_ws;
        u16* Wq_bf  = (u16*)(wsb);
        u16* Wk_bf  = (u16*)(wsb + 4  * MB);
        u16* Wv_bf  = (u16*)(wsb + 8  * MB);
        u16* Wfc_bf = (u16*)(wsb + 12 * MB);
        u16* qb_bf  = (u16*)(wsb + 16 * MB);
        u16* kb_bf  = (u16*)(wsb + 17 * MB);
        u16* vb_bf  = (u16*)(wsb + 18 * MB);
        u16* qh     = (u16*)(wsb + 19 * MB);   // 8 MiB
        u16* kh     = (u16*)(wsb + 27 * MB);   // 8 MiB
        u16* vht    = (u16*)(wsb + 35 * MB);   // 8 MiB
        u16* scores = (u16*)(wsb + 43 * MB);   // [H,L,L] bf16, 16 MiB
        u16* attn_bf  = qh;                    // 16 MiB over qh+kh
        u16* concat   = (u16*)(wsb + 43 * MB); // 8 MiB (scores dead)
        float* fcpart = (float*)(wsb + 51 * MB);// [4,L,512] f32, 8 MiB
        float* fcout  = (float*)(wsb + 59 * MB);// 2 MiB

        {
            CvtArgs a;
            a.src[0] = Wq;  a.dst[0] = Wq_bf;
            a.src[1] = Wk;  a.dst[1] = Wk_bf;
            a.src[2] = Wv;  a.dst[2] = Wv_bf;
            a.src[3] = Wfc; a.dst[3] = Wfc_bf;
            cvt_multi_kernel<<<dim3(1024, 4), blk, 0, stream>>>(a, 262144);
        }

        for (int b = 0; b < NB; ++b) {
            const float* qb = q + (i64)b * LD;
            const float* kb = k + (i64)b * LD;
            const float* vb = v + (i64)b * LD;
            const int* maskb = mask + (i64)b * LL;

            {
                CvtArgs a;
                a.src[0] = qb; a.dst[0] = qb_bf;
                a.src[1] = kb; a.dst[1] = kb_bf;
                a.src[2] = vb; a.dst[2] = vb_bf;
                a.src[3] = vb; a.dst[3] = vb_bf;
                cvt_multi_kernel<<<dim3(256, 3), blk, 0, stream>>>(a, 65536);
            }

            mfma_gemm<true, false><<<dim3(4, 8, NH), blk, 0, stream>>>(
                qb_bf, Wq_bf, qh, nullptr, ND, ND, ND, ND, 1.0f,
                0, 0, 0, ND2, 0, LD);
            mfma_gemm<true, false><<<dim3(4, 8, NH), blk, 0, stream>>>(
                kb_bf, Wk_bf, kh, nullptr, ND, ND, ND, ND, 1.0f,
                0, 0, 0, ND2, 0, LD);
            mfma_gemm<true, false><<<dim3(8, 4, NH), blk, 0, stream>>>(
                Wv_bf, vb_bf, vht, nullptr, ND, ND, ND, NL, 1.0f,
                0, ND2, 0, 0, 0, LD);

            mfma_gemm<true, false><<<dim3(8, 8, NH), blk, 0, stream>>>(
                qh, kh, scores, nullptr, ND, ND, ND, NL, inv_sqrt_d,
                0, LD, 0, LD, 0, LL);

            softmax_fused_kernel<<<dim3(NL, 1), blk, 0, stream>>>(
                scores, maskb, attn_bf, attn_mean + (i64)b * LL, 0, 0, 0, 0);

            mfma_gemm<true, false><<<dim3(4, 8, NH), blk, 0, stream>>>(
                attn_bf, vht, concat, nullptr, NL, NL, NL, NH * ND, 1.0f,
                0, LL, 0, LD, 0, (i64)ND);

            mfma_gemm<false, false><<<dim3(4, 8, 4), blk, 0, stream>>>(
                concat, Wfc_bf, fcpart, nullptr, NL, NH * ND, NH * ND, ND, 1.0f,
                0, NL, 0, NL, 0, LD);
            reduce_fc_kernel<4><<<dim3(2048), blk, 0, stream>>>(fcpart, bfc, fcout, LD);

            ln_kernel<<<dim3(NL), blk, 0, stream>>>(fcout, qb, gamma, beta, out + (i64)b * LD);
        }
    } else {
        // ======================= fp32 fallback (12 MiB) =======================
        float* ws = (float*)d_ws;
        float* qh_h   = ws;
        float* kh_h   = ws + LD;
        float* vh_h   = ws + 2 * LD;
        float* attn_h = ws + 3 * LD;
        float* headout = qh_h;
        float* fcout   = ws + 5 * LD;

        for (int b = 0; b < NB; ++b) {
            const float* qb = q + (i64)b * LD;
            const float* kb = k + (i64)b * LD;
            const float* vb = v + (i64)b * LD;
            const int* maskb = mask + (i64)b * LL;

            for (int h = 0; h < NH; ++h) {
                const i64 wofs = (i64)h * ND2;
                gemm_kernel<true, false, false><<<dim3(8, 16, 1), blk, 0, stream>>>(
                    qb, Wq + wofs, qh_h, nullptr, NL, ND, ND, ND, ND, ND, 1.0f);
                gemm_kernel<true, false, false><<<dim3(8, 16, 1), blk, 0, stream>>>(
                    kb, Wk + wofs, kh_h, nullptr, NL, ND, ND, ND, ND, ND, 1.0f);
                gemm_kernel<true, false, false><<<dim3(8, 16, 1), blk, 0, stream>>>(
                    vb, Wv + wofs, vh_h, nullptr, NL, ND, ND, ND, ND, ND, 1.0f);
                gemm_kernel<true, false, false><<<dim3(16, 16, 1), blk, 0, stream>>>(
                    qh_h, kh_h, attn_h, nullptr, NL, NL, ND, ND, ND, NL, inv_sqrt_d);
                softmax_kernel<<<dim3(NL), blk, 0, stream>>>(attn_h, maskb);
                mean_acc_kernel<<<dim3(4096), blk, 0, stream>>>(
                    attn_h, attn_mean + (i64)b * LL, h == 0 ? 1 : 0);
                gemm_kernel<false, false, false><<<dim3(8, 16, 1), blk, 0, stream>>>(
                    attn_h, vh_h, headout, nullptr, NL, ND, NL, NL, ND, ND, 1.0f);
                if (h == 0)
                    gemm_kernel<true, true, false><<<dim3(8, 16, 1), blk, 0, stream>>>(
                        headout, Wfc + (i64)h * ND, fcout, bfc, NL, ND, ND, ND, NH * ND, ND, 1.0f);
                else
                    gemm_kernel<true, false, true><<<dim3(8, 16, 1), blk, 0, stream>>>(
                        headout, Wfc + (i64)h * ND, fcout, nullptr, NL, ND, ND, ND, NH * ND, ND, 1.0f);
            }
            ln_kernel<<<dim3(NL), blk, 0, stream>>>(fcout, qb, gamma, beta, out + (i64)b * LD);
        }
    }
}

// Round 15
// 257.532 us; speedup vs baseline: 1.0992x; 1.0992x over previous
//
#include <hip/hip_runtime.h>
#include <hip/hip_bf16.h>
#include <cmath>

typedef long long i64;
typedef unsigned short u16;
typedef __attribute__((ext_vector_type(8))) short short8;
typedef __attribute__((ext_vector_type(8))) unsigned short u16x8;
typedef __attribute__((ext_vector_type(4))) float f32x4;
typedef __attribute__((ext_vector_type(4))) int i32x4;

#define NB 4
#define NL 1024
#define ND 512
#define NH 8

__device__ __forceinline__ u16 f2bf(float f) {
    __hip_bfloat16 h = __float2bfloat16(f);
    return __builtin_bit_cast(unsigned short, h);
}
__device__ __forceinline__ float bf2f(u16 u) {
    return __builtin_bit_cast(float, (unsigned)u << 16);
}

// async global->LDS, 16B per lane. LDS dest is wave-uniform base + lane*16.
typedef __attribute__((address_space(3))) u16* lds_u16p;
typedef const __attribute__((address_space(1))) u16* glb_u16p;
__device__ __forceinline__ void gl_lds16(const u16* g, u16* l) {
    __builtin_amdgcn_global_load_lds((glb_u16p)g, (lds_u16p)l, 16, 0, 0);
}

// ---------------------------------------------------------------------------
// fused fp32 -> bf16 convert for up to 8 tensors (blockIdx.y selects)
// ---------------------------------------------------------------------------
struct CvtArgs {
    const float* src[8];
    u16* dst[8];
};

__global__ __launch_bounds__(256) void cvt_multi_kernel(CvtArgs args, int n8)
{
    int i = blockIdx.x * 256 + threadIdx.x;
    if (i >= n8) return;
    const float* __restrict__ src = args.src[blockIdx.y];
    u16* __restrict__ dst = args.dst[blockIdx.y];
    float4 a = ((const float4*)src)[2 * i];
    float4 b = ((const float4*)src)[2 * i + 1];
    u16x8 o;
    o[0] = f2bf(a.x); o[1] = f2bf(a.y); o[2] = f2bf(a.z); o[3] = f2bf(a.w);
    o[4] = f2bf(b.x); o[5] = f2bf(b.y); o[6] = f2bf(b.z); o[7] = f2bf(b.w);
    *(u16x8*)&dst[8 * i] = o;
}

// ---------------------------------------------------------------------------
// bf16 MFMA GEMM, BT-form:  C[m,n] = alpha * sum_k A[m,k]*B[n,k]  (+ bias[n])
// A: [M,K] bf16 (lda), B: [N,K] bf16 (ldb), C: fp32 or bf16 (OUTBF, ldc).
// z-offsets (3 levels): off = (z>>5)*s0 + ((z>>3)&3)*s1 + (z&7)*s2.
// m97 geometry, BK=64, XOR-swizzled LDS (T2), XCD-chunked block swizzle (T1),
// T3/T4 pipeline: double-buffered LDS, raw s_barrier, counted vmcnt(8),
// T5 setprio(1) around the MFMA cluster.
// M,N multiples of 128; K multiple of 64; lda/ldb multiples of 8.
// ---------------------------------------------------------------------------
template <bool OUTBF, bool BIAS>
__global__ __launch_bounds__(256) void mfma_gemm(
    const u16* __restrict__ A, const u16* __restrict__ B,
    void* __restrict__ Cv, const float* __restrict__ bias,
    int K, int lda, int ldb, int ldc, float alpha,
    i64 a_s0, i64 a_s1, i64 a_s2,
    i64 b_s0, i64 b_s1, i64 b_s2,
    i64 c_s0, i64 c_s1, i64 c_s2)
{
    // ---- XCD-chunked swizzle: contiguous work chunk per XCD (L2 locality)
    const int gxy  = gridDim.x * gridDim.y;
    const int nblk = gxy * gridDim.z;
    const int lin  = blockIdx.x + gridDim.x * blockIdx.y + gxy * blockIdx.z;
    const int swz  = (lin & 7) * (nblk >> 3) + (lin >> 3);
    const int bz   = swz / gxy;
    const int rxy  = swz - bz * gxy;
    const int by   = rxy / gridDim.x;
    const int bx   = rxy - by * gridDim.x;

    const int zq = bz >> 5, zh = (bz >> 3) & 3, zl = bz & 7;
    A += (i64)zq * a_s0 + (i64)zh * a_s1 + (i64)zl * a_s2;
    B += (i64)zq * b_s0 + (i64)zh * b_s1 + (i64)zl * b_s2;
    const i64 coff = (i64)zq * c_s0 + (i64)zh * c_s1 + (i64)zl * c_s2;

    __shared__ alignas(16) u16 As[2 * 128 * 64];   // double buffer
    __shared__ alignas(16) u16 Bs[2 * 128 * 64];

    const int tid  = threadIdx.x;
    const int lane = tid & 63;
    const int wave = tid >> 6;           // 0..3
    const int wr   = (wave >> 1) * 64;   // wave row offset: 0,64
    const int wc   = (wave & 1) * 64;    // wave col offset: 0,64
    const int lrow = lane & 15;
    const int kblk = lane >> 4;          // 0..3
    const int rsw  = (lrow & 7) * 8;     // read-side XOR (u16 units)
    const int m0   = by * 128;
    const int n0   = bx * 128;

    // staging: wave w stages rows [32w,32w+32); 4 issues of 8 rows for A, B.
    // lane l -> rel row (l>>3), SWIZZLED source chunk ((l&7) ^ (l>>3)).
    const int srow0 = wave * 32;
    const int lrel  = lane >> 3;               // 0..7
    const int grow  = srow0 + lrel;
    const int gchk  = ((lane & 7) ^ lrel) * 8; // swizzled source chunk (u16)

    f32x4 acc[4][4];
    #pragma unroll
    for (int i = 0; i < 4; ++i)
        #pragma unroll
        for (int j = 0; j < 4; ++j)
            acc[i][j] = (f32x4){0.f, 0.f, 0.f, 0.f};

    const int nt = K >> 6;   // K / 64 tiles

    // prologue: stage tile 0 into buffer 0
    #pragma unroll
    for (int j = 0; j < 4; ++j)
        gl_lds16(&A[(i64)(m0 + grow + 8 * j) * lda + gchk],
                 &As[(srow0 + 8 * j) * 64]);
    #pragma unroll
    for (int j = 0; j < 4; ++j)
        gl_lds16(&B[(i64)(n0 + grow + 8 * j) * ldb + gchk],
                 &Bs[(srow0 + 8 * j) * 64]);

    int cur = 0;
    for (int t = 0; t < nt; ++t) {
        const int nxt = cur ^ 1;
        if (t + 1 < nt) {
            const int k0n = (t + 1) << 6;
            #pragma unroll
            for (int j = 0; j < 4; ++j)
                gl_lds16(&A[(i64)(m0 + grow + 8 * j) * lda + k0n + gchk],
                         &As[nxt * 8192 + (srow0 + 8 * j) * 64]);
            #pragma unroll
            for (int j = 0; j < 4; ++j)
                gl_lds16(&B[(i64)(n0 + grow + 8 * j) * ldb + k0n + gchk],
                         &Bs[nxt * 8192 + (srow0 + 8 * j) * 64]);
            // wait only for the OLDEST 8 (current tile); prefetch stays in flight
            asm volatile("s_waitcnt vmcnt(8)" ::: "memory");
        } else {
            asm volatile("s_waitcnt vmcnt(0)" ::: "memory");
        }
        asm volatile("s_barrier" ::: "memory");   // buf[cur] ready on all waves

        const u16* Ab = &As[cur * 8192];
        const u16* Bb = &Bs[cur * 8192];
        __builtin_amdgcn_s_setprio(1);
        #pragma unroll
        for (int kk = 0; kk < 2; ++kk) {
            short8 af[4], bg[4];
            #pragma unroll
            for (int m = 0; m < 4; ++m)
                af[m] = *(const short8*)&Ab[(wr + m * 16 + lrow) * 64 +
                                            (((kk * 32) + kblk * 8) ^ rsw)];
            #pragma unroll
            for (int n = 0; n < 4; ++n)
                bg[n] = *(const short8*)&Bb[(wc + n * 16 + lrow) * 64 +
                                            (((kk * 32) + kblk * 8) ^ rsw)];

            #pragma unroll
            for (int m = 0; m < 4; ++m)
                #pragma unroll
                for (int n = 0; n < 4; ++n)
                    acc[m][n] = __builtin_amdgcn_mfma_f32_16x16x32_bf16(
                        af[m], bg[n], acc[m][n], 0, 0, 0);
        }
        __builtin_amdgcn_s_setprio(0);
        asm volatile("s_barrier" ::: "memory");   // all reads of buf[cur] done
        cur = nxt;
    }

    // epilogue: C/D layout col = lane&15, row = 4*(lane>>4)+reg
    #pragma unroll
    for (int m = 0; m < 4; ++m) {
        #pragma unroll
        for (int n = 0; n < 4; ++n) {
            const int col = n0 + wc + n * 16 + lrow;
            float bv = BIAS ? bias[col] : 0.f;
            #pragma unroll
            for (int r = 0; r < 4; ++r) {
                const int row = m0 + wr + m * 16 + kblk * 4 + r;
                float val = acc[m][n][r] * alpha + bv;
                if (OUTBF)
                    ((u16*)Cv)[coff + (i64)row * ldc + col] = f2bf(val);
                else
                    ((float*)Cv)[coff + (i64)row * ldc + col] = val;
            }
        }
    }
}

// ---------------------------------------------------------------------------
// split-K reduce + bias: out[i] = sum_p part[p*pstride + i] + bias[i % ND]
// ---------------------------------------------------------------------------
template <int P>
__global__ __launch_bounds__(256) void reduce_fc_kernel(
    const float* __restrict__ part, const float* __restrict__ bias,
    float* __restrict__ outp, i64 pstride)
{
    i64 idx = (i64)blockIdx.x * 256 + threadIdx.x;
    float s = bias[idx & (ND - 1)];
    #pragma unroll
    for (int p = 0; p < P; ++p) s += part[(i64)p * pstride + idx];
    outp[idx] = s;
}

// ---------------------------------------------------------------------------
__device__ __forceinline__ float wave_red_sum(float v) {
    #pragma unroll
    for (int o = 32; o > 0; o >>= 1) v += __shfl_down(v, o, 64);
    return v;
}

// ---------------------------------------------------------------------------
// Barrier-free fused masked softmax + renorm + head-mean.
// Wave w handles heads {w, w+4} of one (batch, q-row); full-row reductions
// via 6-step shfl_xor butterflies (no __syncthreads in head loop).
// ---------------------------------------------------------------------------
__global__ __launch_bounds__(256) void softmax_fused_kernel(
    const u16* __restrict__ scores, const int* __restrict__ mask,
    u16* __restrict__ attn_bf, float* __restrict__ amean,
    i64 s_bstride, i64 m_bstride, i64 a_bstride, i64 o_bstride)
{
    const int qrow = blockIdx.x;
    const int bb   = blockIdx.y;
    const u16* sbase = scores + (i64)bb * s_bstride;
    const int* mrow = mask + (i64)bb * m_bstride + (i64)qrow * NL;
    u16* abase = attn_bf + (i64)bb * a_bstride;
    float* orow = amean + (i64)bb * o_bstride + (i64)qrow * NL;

    const int tid  = threadIdx.x;
    const int lane = tid & 63;
    const int wave = tid >> 6;           // 0..3

    __shared__ float wsum[4][NL];        // per-wave head-sum partials

    const int e0 = lane * 8;
    const int e1 = 512 + lane * 8;

    float mv[16];
    {
        i32x4 m0a = *(const i32x4*)&mrow[e0];
        i32x4 m0b = *(const i32x4*)&mrow[e0 + 4];
        i32x4 m1a = *(const i32x4*)&mrow[e1];
        i32x4 m1b = *(const i32x4*)&mrow[e1 + 4];
        #pragma unroll
        for (int i = 0; i < 4; ++i) {
            mv[i]      = (float)m0a[i];
            mv[4 + i]  = (float)m0b[i];
            mv[8 + i]  = (float)m1a[i];
            mv[12 + i] = (float)m1b[i];
        }
    }

    float msum[16];
    #pragma unroll
    for (int i = 0; i < 16; ++i) msum[i] = 0.f;

    #pragma unroll
    for (int hh = 0; hh < 2; ++hh) {
        const int h = wave + hh * 4;
        const u16* srow_p = sbase + ((i64)h * NL + qrow) * NL;
        u16* arow_p = abase + ((i64)h * NL + qrow) * NL;

        u16x8 s0 = *(const u16x8*)&srow_p[e0];
        u16x8 s1 = *(const u16x8*)&srow_p[e1];

        float zv[16];
        float lmax = -1e30f;
        #pragma unroll
        for (int i = 0; i < 8; ++i) {
            zv[i]     = bf2f(s0[i]) * mv[i];
            zv[8 + i] = bf2f(s1[i]) * mv[8 + i];
        }
        #pragma unroll
        for (int i = 0; i < 16; ++i) lmax = fmaxf(lmax, zv[i]);
        #pragma unroll
        for (int o = 1; o < 64; o <<= 1)
            lmax = fmaxf(lmax, __shfl_xor(lmax, o, 64));

        float e[16];
        float ls = 0.f;
        #pragma unroll
        for (int i = 0; i < 16; ++i) { e[i] = __expf(zv[i] - lmax); ls += e[i]; }
        #pragma unroll
        for (int o = 1; o < 64; o <<= 1) ls += __shfl_xor(ls, o, 64);

        float ls2 = 0.f;
        #pragma unroll
        for (int i = 0; i < 16; ++i) { e[i] = e[i] / ls * mv[i]; ls2 += e[i]; }
        #pragma unroll
        for (int o = 1; o < 64; o <<= 1) ls2 += __shfl_xor(ls2, o, 64);

        const float inv = 1.0f / (ls2 + 1e-13f);
        u16x8 o0, o1;
        #pragma unroll
        for (int i = 0; i < 8; ++i) {
            float p0 = e[i] * inv;
            float p1 = e[8 + i] * inv;
            o0[i] = f2bf(p0);
            o1[i] = f2bf(p1);
            msum[i]     += p0;
            msum[8 + i] += p1;
        }
        *(u16x8*)&arow_p[e0] = o0;
        *(u16x8*)&arow_p[e1] = o1;
    }

    #pragma unroll
    for (int i = 0; i < 8; ++i) {
        wsum[wave][e0 + i] = msum[i];
        wsum[wave][e1 + i] = msum[8 + i];
    }
    __syncthreads();
    #pragma unroll
    for (int i = 0; i < 4; ++i) {
        int j = tid + i * 256;
        orow[j] = (wsum[0][j] + wsum[1][j] + wsum[2][j] + wsum[3][j]) * 0.125f;
    }
}

// ---------------------------------------------------------------------------
// residual add + LayerNorm over D=512. grid: rows, 256 threads (2 elem/thr)
// ---------------------------------------------------------------------------
__global__ __launch_bounds__(256) void ln_kernel(
    const float* __restrict__ fcout, const float* __restrict__ resid,
    const float* __restrict__ gamma, const float* __restrict__ beta,
    float* __restrict__ out)
{
    const int row = blockIdx.x;
    const float* xr = fcout + (i64)row * ND;
    const float* rr = resid + (i64)row * ND;
    const int tid = threadIdx.x;
    const int lane = tid & 63, wid = tid >> 6;
    __shared__ float red[8];

    float x0 = xr[tid] + rr[tid];
    float x1 = xr[tid + 256] + rr[tid + 256];
    float s  = x0 + x1;
    float s2 = x0 * x0 + x1 * x1;
    s  = wave_red_sum(s);
    s2 = wave_red_sum(s2);
    if (lane == 0) { red[wid] = s; red[4 + wid] = s2; }
    __syncthreads();
    const float S  = red[0] + red[1] + red[2] + red[3];
    const float S2 = red[4] + red[5] + red[6] + red[7];
    const float mu  = S * (1.0f / ND);
    const float var = S2 * (1.0f / ND) - mu * mu;
    const float inv = rsqrtf(var + 1e-5f);

    out[(i64)row * ND + tid]       = (x0 - mu) * inv * gamma[tid] + beta[tid];
    out[(i64)row * ND + tid + 256] = (x1 - mu) * inv * gamma[tid + 256] + beta[tid + 256];
}

// ===========================================================================
// Fallback fp32 path (small workspace): per-(b,h) scalar GEMM pipeline.
// ===========================================================================
template <bool BT, bool BIAS, bool ACC>
__global__ __launch_bounds__(256) void gemm_kernel(
    const float* __restrict__ A, const float* __restrict__ B,
    float* __restrict__ C, const float* __restrict__ bias,
    int M, int N, int K, int lda, int ldb, int ldc, float alpha)
{
    __shared__ float Asf[16][68];
    __shared__ float Bsf[16][68];
    const int tid = threadIdx.x;
    const int tx = tid & 15, ty = tid >> 4;
    const int m0 = blockIdx.y * 64, n0 = blockIdx.x * 64;
    float acc[4][4] = {};

    for (int k0 = 0; k0 < K; k0 += 16) {
        {
            int r = tid >> 2, kq = (tid & 3) << 2;
            float4 a = *reinterpret_cast<const float4*>(&A[(i64)(m0 + r) * lda + k0 + kq]);
            Asf[kq][r] = a.x; Asf[kq + 1][r] = a.y; Asf[kq + 2][r] = a.z; Asf[kq + 3][r] = a.w;
        }
        if (BT) {
            int r = tid >> 2, kq = (tid & 3) << 2;
            float4 b = *reinterpret_cast<const float4*>(&B[(i64)(n0 + r) * ldb + k0 + kq]);
            Bsf[kq][r] = b.x; Bsf[kq + 1][r] = b.y; Bsf[kq + 2][r] = b.z; Bsf[kq + 3][r] = b.w;
        } else {
            int kk = tid >> 4, n4 = (tid & 15) << 2;
            float4 b = *reinterpret_cast<const float4*>(&B[(i64)(k0 + kk) * ldb + n0 + n4]);
            *reinterpret_cast<float4*>(&Bsf[kk][n4]) = b;
        }
        __syncthreads();
        #pragma unroll
        for (int kk = 0; kk < 16; ++kk) {
            float4 a4 = *reinterpret_cast<const float4*>(&Asf[kk][ty << 2]);
            float4 b4 = *reinterpret_cast<const float4*>(&Bsf[kk][tx << 2]);
            float a[4] = {a4.x, a4.y, a4.z, a4.w};
            float b[4] = {b4.x, b4.y, b4.z, b4.w};
            #pragma unroll
            for (int i = 0; i < 4; ++i)
                #pragma unroll
                for (int j = 0; j < 4; ++j)
                    acc[i][j] = fmaf(a[i], b[j], acc[i][j]);
        }
        __syncthreads();
    }
    #pragma unroll
    for (int i = 0; i < 4; ++i) {
        int m = m0 + (ty << 2) + i;
        #pragma unroll
        for (int j = 0; j < 4; ++j) {
            int n = n0 + (tx << 2) + j;
            float val = acc[i][j] * alpha;
            if (BIAS) val += bias[n];
            i64 idx = (i64)m * ldc + n;
            if (ACC) C[idx] += val; else C[idx] = val;
        }
    }
}

__device__ __forceinline__ float wave_red_max(float v) {
    #pragma unroll
    for (int o = 32; o > 0; o >>= 1) v = fmaxf(v, __shfl_down(v, o, 64));
    return v;
}

__global__ __launch_bounds__(256) void softmax_kernel(
    float* __restrict__ attn, const int* __restrict__ mask)
{
    const int qrow = blockIdx.x;
    float* row = attn + (i64)qrow * NL;
    const int* mrow = mask + (i64)qrow * NL;
    const int tid = threadIdx.x;
    const int lane = tid & 63, wid = tid >> 6;
    __shared__ float red[4];

    float zv[4], mv[4];
    float lmax = -1e30f;
    #pragma unroll
    for (int i = 0; i < 4; ++i) {
        mv[i] = (float)mrow[tid + i * 256];
        zv[i] = row[tid + i * 256] * mv[i];
        lmax  = fmaxf(lmax, zv[i]);
    }
    float wv = wave_red_max(lmax);
    if (lane == 0) red[wid] = wv;
    __syncthreads();
    const float gmax = fmaxf(fmaxf(red[0], red[1]), fmaxf(red[2], red[3]));
    float e[4]; float ls = 0.f;
    #pragma unroll
    for (int i = 0; i < 4; ++i) { e[i] = __expf(zv[i] - gmax); ls += e[i]; }
    __syncthreads();
    wv = wave_red_sum(ls);
    if (lane == 0) red[wid] = wv;
    __syncthreads();
    const float S1 = red[0] + red[1] + red[2] + red[3];
    float ls2 = 0.f;
    #pragma unroll
    for (int i = 0; i < 4; ++i) { e[i] = e[i] / S1 * mv[i]; ls2 += e[i]; }
    __syncthreads();
    wv = wave_red_sum(ls2);
    if (lane == 0) red[wid] = wv;
    __syncthreads();
    const float S2 = red[0] + red[1] + red[2] + red[3];
    const float inv = 1.0f / (S2 + 1e-13f);
    #pragma unroll
    for (int i = 0; i < 4; ++i) row[tid + i * 256] = e[i] * inv;
}

__global__ __launch_bounds__(256) void mean_acc_kernel(
    const float* __restrict__ attn, float* __restrict__ out, int first)
{
    i64 idx = (i64)blockIdx.x * 256 + threadIdx.x;
    float v = attn[idx] * 0.125f;
    out[idx] = first ? v : (out[idx] + v);
}

// ---------------------------------------------------------------------------
extern "C" void kernel_launch(void* const* d_in, const int* in_sizes, int n_in,
                              void* d_out, int out_size, void* d_ws, size_t ws_size,
                              hipStream_t stream)
{
    const float* q     = (const float*)d_in[0];
    const int*   mask  = (const int*)  d_in[1];
    const float* k     = (const float*)d_in[2];
    const float* v     = (const float*)d_in[3];
    const float* Wq    = (const float*)d_in[4];
    const float* Wk    = (const float*)d_in[5];
    const float* Wv    = (const float*)d_in[6];
    const float* Wfc   = (const float*)d_in[7];
    const float* bfc   = (const float*)d_in[8];
    const float* gamma = (const float*)d_in[9];
    const float* beta  = (const float*)d_in[10];

    float* out       = (float*)d_out;                 // [B,L,D]
    float* attn_mean = out + (i64)NB * NL * ND;       // [B,L,L]

    const float inv_sqrt_d = 0.04419417382415922f;    // 1/sqrt(512)
    const i64 LD  = (i64)NL * ND;                     // 524288
    const i64 LL  = (i64)NL * NL;                     // 1048576
    const i64 ND2 = (i64)ND * ND;                     // 262144
    const i64 HLD = (i64)NH * LD;                     // 4194304
    const i64 HLL = (i64)NH * LL;                     // 8388608
    dim3 blk(256);

    const size_t MB = 1048576;

    if (ws_size >= 196 * MB) {
        // ================= full-batch bf16 MFMA path (196 MiB) =================
        char* wsb = (char*)d_ws;
        u16* Wq_bf  = (u16*)(wsb);              // 4 MiB each; Wq/Wk CONTIGUOUS
        u16* Wk_bf  = (u16*)(wsb + 4   * MB);
        u16* Wv_bf  = (u16*)(wsb + 8   * MB);
        u16* Wfc_bf = (u16*)(wsb + 12  * MB);
        u16* q_bf   = (u16*)(wsb + 16  * MB);   // q/k CONTIGUOUS (4 MiB each)
        u16* k_bf   = (u16*)(wsb + 20  * MB);
        u16* v_bf   = (u16*)(wsb + 24  * MB);
        u16* qh     = (u16*)(wsb + 28  * MB);   // qh/kh CONTIGUOUS (32 MiB each)
        u16* kh     = (u16*)(wsb + 60  * MB);
        u16* vht    = (u16*)(wsb + 92  * MB);   // [B,H,D,L] bf16, 32 MiB
        u16* scores = (u16*)(wsb + 124 * MB);   // [B,H,L,L] bf16, 64 MiB -> 188
        u16* attn_bf  = qh;                      // [B,H,L,L] bf16, over qh+kh
        u16* concat   = (u16*)(wsb + 124 * MB);  // [B*L,H*D] bf16, 32 MiB (scores dead)
        float* fcpart = (float*)(wsb + 156 * MB);// [4, B*L, 512] f32, 32 MiB
        float* fcout  = (float*)(wsb + 188 * MB);// [B*L, 512] f32, 8 MiB -> 196

        // ---- all 7 tensors -> bf16 in ONE launch (each is 2M floats)
        {
            CvtArgs a;
            a.src[0] = Wq;  a.dst[0] = Wq_bf;
            a.src[1] = Wk;  a.dst[1] = Wk_bf;
            a.src[2] = Wv;  a.dst[2] = Wv_bf;
            a.src[3] = Wfc; a.dst[3] = Wfc_bf;
            a.src[4] = q;   a.dst[4] = q_bf;
            a.src[5] = k;   a.dst[5] = k_bf;
            a.src[6] = v;   a.dst[6] = v_bf;
            a.src[7] = v;   a.dst[7] = v_bf;   // unused (y<7)
            cvt_multi_kernel<<<dim3(1024, 7), blk, 0, stream>>>(a, 262144);
        }

        // ---- fused Q+K projections: z = sel*32 + b*8 + h (64)
        // A = {q_bf,k_bf}[sel] + b*LD ; B = {Wq,Wk}[sel] + h*ND2 ;
        // C = {qh,kh}[sel] + b*HLD + h*LD.  (4*LD = one tensor; 4*HLD = one out)
        mfma_gemm<true, false><<<dim3(4, 8, 64), blk, 0, stream>>>(
            q_bf, Wq_bf, qh, nullptr, ND, ND, ND, ND, 1.0f,
            4 * LD, LD, 0,   8 * ND2, 0, ND2,   4 * HLD, HLD, LD);
        // V projection (operands swapped): vht[b,h,e,l] = Wv[h,e,:] . v[b,l,:]
        mfma_gemm<true, false><<<dim3(8, 4, 32), blk, 0, stream>>>(
            Wv_bf, v_bf, vht, nullptr, ND, ND, ND, NL, 1.0f,
            0, 0, ND2,   0, LD, 0,   0, HLD, LD);

        // ---- scores[b,h,q,k] = (1/sqrt(D)) qh . kh  -> bf16
        mfma_gemm<true, false><<<dim3(8, 8, 32), blk, 0, stream>>>(
            qh, kh, scores, nullptr, ND, ND, ND, NL, inv_sqrt_d,
            0, HLD, LD,   0, HLD, LD,   0, HLL, LL);

        // ---- softmax + renorm + bf16 attn + head-mean (all batches)
        softmax_fused_kernel<<<dim3(NL, NB), blk, 0, stream>>>(
            scores, mask, attn_bf, attn_mean, HLL, LL, HLL, LL);

        // ---- PV: concat[b*L+l, h*512+e] = sum_k attn[b,h,l,k] vht[b,h,e,k]
        mfma_gemm<true, false><<<dim3(4, 8, 32), blk, 0, stream>>>(
            attn_bf, vht, concat, nullptr, NL, NL, NL, NH * ND, 1.0f,
            0, HLL, LL,   0, HLD, LD,   0, (i64)NL * NH * ND, (i64)ND);

        // ---- fc split-K: z = K-chunk (4 x 1024)
        mfma_gemm<false, false><<<dim3(4, 32, 4), blk, 0, stream>>>(
            concat, Wfc_bf, fcpart, nullptr, NL, NH * ND, NH * ND, ND, 1.0f,
            0, 0, NL,   0, 0, NL,   0, 0, (i64)NB * NL * ND);
        reduce_fc_kernel<4><<<dim3(8192), blk, 0, stream>>>(
            fcpart, bfc, fcout, (i64)NB * NL * ND);

        // ---- residual + LayerNorm (all batches)
        ln_kernel<<<dim3(NB * NL), blk, 0, stream>>>(fcout, q, gamma, beta, out);

    } else if (ws_size >= 64 * MB) {
        // ================= per-batch bf16 MFMA path (61 MiB) =================
        char* wsb = (char*)d_ws;
        u16* Wq_bf  = (u16*)(wsb);
        u16* Wk_bf  = (u16*)(wsb + 4  * MB);
        u16* Wv_bf  = (u16*)(wsb + 8  * MB);
        u16* Wfc_bf = (u16*)(wsb + 12 * MB);
        u16* qb_bf  = (u16*)(wsb + 16 * MB);
        u16* kb_bf  = (u16*)(wsb + 17 * MB);
        u16* vb_bf  = (u16*)(wsb + 18 * MB);
        u16* qh     = (u16*)(wsb + 19 * MB);   // 8 MiB
        u16* kh     = (u16*)(wsb + 27 * MB);   // 8 MiB
        u16* vht    = (u16*)(wsb + 35 * MB);   // 8 MiB
        u16* scores = (u16*)(wsb + 43 * MB);   // [H,L,L] bf16, 16 MiB
        u16* attn_bf  = qh;                    // 16 MiB over qh+kh
        u16* concat   = (u16*)(wsb + 43 * MB); // 8 MiB (scores dead)
        float* fcpart = (float*)(wsb + 51 * MB);// [4,L,512] f32, 8 MiB
        float* fcout  = (float*)(wsb + 59 * MB);// 2 MiB

        {
            CvtArgs a;
            a.src[0] = Wq;  a.dst[0] = Wq_bf;
            a.src[1] = Wk;  a.dst[1] = Wk_bf;
            a.src[2] = Wv;  a.dst[2] = Wv_bf;
            a.src[3] = Wfc; a.dst[3] = Wfc_bf;
            a.src[4] = Wq;  a.dst[4] = Wq_bf;  // unused
            a.src[5] = Wq;  a.dst[5] = Wq_bf;
            a.src[6] = Wq;  a.dst[6] = Wq_bf;
            a.src[7] = Wq;  a.dst[7] = Wq_bf;
            cvt_multi_kernel<<<dim3(1024, 4), blk, 0, stream>>>(a, 262144);
        }

        for (int b = 0; b < NB; ++b) {
            const float* qb = q + (i64)b * LD;
            const float* kb = k + (i64)b * LD;
            const float* vb = v + (i64)b * LD;
            const int* maskb = mask + (i64)b * LL;

            {
                CvtArgs a;
                a.src[0] = qb; a.dst[0] = qb_bf;
                a.src[1] = kb; a.dst[1] = kb_bf;
                a.src[2] = vb; a.dst[2] = vb_bf;
                a.src[3] = vb; a.dst[3] = vb_bf;
                a.src[4] = vb; a.dst[4] = vb_bf;
                a.src[5] = vb; a.dst[5] = vb_bf;
                a.src[6] = vb; a.dst[6] = vb_bf;
                a.src[7] = vb; a.dst[7] = vb_bf;
                cvt_multi_kernel<<<dim3(256, 3), blk, 0, stream>>>(a, 65536);
            }

            mfma_gemm<true, false><<<dim3(4, 8, NH), blk, 0, stream>>>(
                qb_bf, Wq_bf, qh, nullptr, ND, ND, ND, ND, 1.0f,
                0, 0, 0,   0, 0, ND2,   0, 0, LD);
            mfma_gemm<true, false><<<dim3(4, 8, NH), blk, 0, stream>>>(
                kb_bf, Wk_bf, kh, nullptr, ND, ND, ND, ND, 1.0f,
                0, 0, 0,   0, 0, ND2,   0, 0, LD);
            mfma_gemm<true, false><<<dim3(8, 4, NH), blk, 0, stream>>>(
                Wv_bf, vb_bf, vht, nullptr, ND, ND, ND, NL, 1.0f,
                0, 0, ND2,   0, 0, 0,   0, 0, LD);

            mfma_gemm<true, false><<<dim3(8, 8, NH), blk, 0, stream>>>(
                qh, kh, scores, nullptr, ND, ND, ND, NL, inv_sqrt_d,
                0, 0, LD,   0, 0, LD,   0, 0, LL);

            softmax_fused_kernel<<<dim3(NL, 1), blk, 0, stream>>>(
                scores, maskb, attn_bf, attn_mean + (i64)b * LL, 0, 0, 0, 0);

            mfma_gemm<true, false><<<dim3(4, 8, NH), blk, 0, stream>>>(
                attn_bf, vht, concat, nullptr, NL, NL, NL, NH * ND, 1.0f,
                0, 0, LL,   0, 0, LD,   0, 0, (i64)ND);

            mfma_gemm<false, false><<<dim3(4, 8, 4), blk, 0, stream>>>(
                concat, Wfc_bf, fcpart, nullptr, NL, NH * ND, NH * ND, ND, 1.0f,
                0, 0, NL,   0, 0, NL,   0, 0, LD);
            reduce_fc_kernel<4><<<dim3(2048), blk, 0, stream>>>(fcpart, bfc, fcout, LD);

            ln_kernel<<<dim3(NL), blk, 0, stream>>>(fcout, qb, gamma, beta, out + (i64)b * LD);
        }
    } else {
        // ======================= fp32 fallback (12 MiB) =======================
        float* ws = (float*)d_ws;
        float* qh_h   = ws;
        float* kh_h   = ws + LD;
        float* vh_h   = ws + 2 * LD;
        float* attn_h = ws + 3 * LD;
        float* headout = qh_h;
        float* fcout   = ws + 5 * LD;

        for (int b = 0; b < NB; ++b) {
            const float* qb = q + (i64)b * LD;
            const float* kb = k + (i64)b * LD;
            const float* vb = v + (i64)b * LD;
            const int* maskb = mask + (i64)b * LL;

            for (int h = 0; h < NH; ++h) {
                const i64 wofs = (i64)h * ND2;
                gemm_kernel<true, false, false><<<dim3(8, 16, 1), blk, 0, stream>>>(
                    qb, Wq + wofs, qh_h, nullptr, NL, ND, ND, ND, ND, ND, 1.0f);
                gemm_kernel<true, false, false><<<dim3(8, 16, 1), blk, 0, stream>>>(
                    kb, Wk + wofs, kh_h, nullptr, NL, ND, ND, ND, ND, ND, 1.0f);
                gemm_kernel<true, false, false><<<dim3(8, 16, 1), blk, 0, stream>>>(
                    vb, Wv + wofs, vh_h, nullptr, NL, ND, ND, ND, ND, ND, 1.0f);
                gemm_kernel<true, false, false><<<dim3(16, 16, 1), blk, 0, stream>>>(
                    qh_h, kh_h, attn_h, nullptr, NL, NL, ND, ND, ND, NL, inv_sqrt_d);
                softmax_kernel<<<dim3(NL), blk, 0, stream>>>(attn_h, maskb);
                mean_acc_kernel<<<dim3(4096), blk, 0, stream>>>(
                    attn_h, attn_mean + (i64)b * LL, h == 0 ? 1 : 0);
                gemm_kernel<false, false, false><<<dim3(8, 16, 1), blk, 0, stream>>>(
                    attn_h, vh_h, headout, nullptr, NL, ND, NL, NL, ND, ND, 1.0f);
                if (h == 0)
                    gemm_kernel<true, true, false><<<dim3(8, 16, 1), blk, 0, stream>>>(
                        headout, Wfc + (i64)h * ND, fcout, bfc, NL, ND, ND, ND, NH * ND, ND, 1.0f);
                else
                    gemm_kernel<true, false, true><<<dim3(8, 16, 1), blk, 0, stream>>>(
                        headout, Wfc + (i64)h * ND, fcout, nullptr, NL, ND, ND, ND, NH * ND, ND, 1.0f);
            }
            ln_kernel<<<dim3(NL), blk, 0, stream>>>(fcout, qb, gamma, beta, out + (i64)b * LD);
        }
    }
}

// Round 16
// 250.613 us; speedup vs baseline: 1.1295x; 1.0276x over previous
//
#include <hip/hip_runtime.h>
#include <hip/hip_bf16.h>
#include <cmath>

typedef long long i64;
typedef unsigned short u16;
typedef __attribute__((ext_vector_type(8))) short short8;
typedef __attribute__((ext_vector_type(8))) unsigned short u16x8;
typedef __attribute__((ext_vector_type(4))) float f32x4;
typedef __attribute__((ext_vector_type(4))) int i32x4;

#define NB 4
#define NL 1024
#define ND 512
#define NH 8

__device__ __forceinline__ u16 f2bf(float f) {
    __hip_bfloat16 h = __float2bfloat16(f);
    return __builtin_bit_cast(unsigned short, h);
}
__device__ __forceinline__ float bf2f(u16 u) {
    return __builtin_bit_cast(float, (unsigned)u << 16);
}

// async global->LDS, 16B per lane. LDS dest is wave-uniform base + lane*16.
typedef __attribute__((address_space(3))) u16* lds_u16p;
typedef const __attribute__((address_space(1))) u16* glb_u16p;
__device__ __forceinline__ void gl_lds16(const u16* g, u16* l) {
    __builtin_amdgcn_global_load_lds((glb_u16p)g, (lds_u16p)l, 16, 0, 0);
}

// ---------------------------------------------------------------------------
// fused fp32 -> bf16 convert for up to 8 tensors (blockIdx.y selects)
// ---------------------------------------------------------------------------
struct CvtArgs {
    const float* src[8];
    u16* dst[8];
};

__global__ __launch_bounds__(256) void cvt_multi_kernel(CvtArgs args, int n8)
{
    int i = blockIdx.x * 256 + threadIdx.x;
    if (i >= n8) return;
    const float* __restrict__ src = args.src[blockIdx.y];
    u16* __restrict__ dst = args.dst[blockIdx.y];
    float4 a = ((const float4*)src)[2 * i];
    float4 b = ((const float4*)src)[2 * i + 1];
    u16x8 o;
    o[0] = f2bf(a.x); o[1] = f2bf(a.y); o[2] = f2bf(a.z); o[3] = f2bf(a.w);
    o[4] = f2bf(b.x); o[5] = f2bf(b.y); o[6] = f2bf(b.z); o[7] = f2bf(b.w);
    *(u16x8*)&dst[8 * i] = o;
}

// ---------------------------------------------------------------------------
// bf16 MFMA GEMM, BT-form:  C[m,n] = alpha * sum_k A[m,k]*B[n,k]  (+ bias[n])
// A: [M,K] bf16 (lda), B: [N,K] bf16 (ldb), C: fp32 or bf16 (OUTBF, ldc).
// z-offsets (3 levels): off = (z>>5)*s0 + ((z>>3)&3)*s1 + (z&7)*s2.
// m97 geometry, BK=64, XOR-swizzled LDS (T2), XCD-chunked block swizzle (T1),
// T3/T4 pipeline: double-buffered LDS, raw s_barrier, counted vmcnt(8),
// T5 setprio(1) around the MFMA cluster.
// M,N multiples of 128; K multiple of 64; lda/ldb multiples of 8.
// ---------------------------------------------------------------------------
template <bool OUTBF, bool BIAS>
__global__ __launch_bounds__(256) void mfma_gemm(
    const u16* __restrict__ A, const u16* __restrict__ B,
    void* __restrict__ Cv, const float* __restrict__ bias,
    int K, int lda, int ldb, int ldc, float alpha,
    i64 a_s0, i64 a_s1, i64 a_s2,
    i64 b_s0, i64 b_s1, i64 b_s2,
    i64 c_s0, i64 c_s1, i64 c_s2)
{
    // ---- XCD-chunked swizzle: contiguous work chunk per XCD (L2 locality)
    const int gxy  = gridDim.x * gridDim.y;
    const int nblk = gxy * gridDim.z;
    const int lin  = blockIdx.x + gridDim.x * blockIdx.y + gxy * blockIdx.z;
    const int swz  = (lin & 7) * (nblk >> 3) + (lin >> 3);
    const int bz   = swz / gxy;
    const int rxy  = swz - bz * gxy;
    const int by   = rxy / gridDim.x;
    const int bx   = rxy - by * gridDim.x;

    const int zq = bz >> 5, zh = (bz >> 3) & 3, zl = bz & 7;
    A += (i64)zq * a_s0 + (i64)zh * a_s1 + (i64)zl * a_s2;
    B += (i64)zq * b_s0 + (i64)zh * b_s1 + (i64)zl * b_s2;
    const i64 coff = (i64)zq * c_s0 + (i64)zh * c_s1 + (i64)zl * c_s2;

    __shared__ alignas(16) u16 As[2 * 128 * 64];   // double buffer
    __shared__ alignas(16) u16 Bs[2 * 128 * 64];

    const int tid  = threadIdx.x;
    const int lane = tid & 63;
    const int wave = tid >> 6;           // 0..3
    const int wr   = (wave >> 1) * 64;   // wave row offset: 0,64
    const int wc   = (wave & 1) * 64;    // wave col offset: 0,64
    const int lrow = lane & 15;
    const int kblk = lane >> 4;          // 0..3
    const int rsw  = (lrow & 7) * 8;     // read-side XOR (u16 units)
    const int m0   = by * 128;
    const int n0   = bx * 128;

    // staging: wave w stages rows [32w,32w+32); 4 issues of 8 rows for A, B.
    // lane l -> rel row (l>>3), SWIZZLED source chunk ((l&7) ^ (l>>3)).
    const int srow0 = wave * 32;
    const int lrel  = lane >> 3;               // 0..7
    const int grow  = srow0 + lrel;
    const int gchk  = ((lane & 7) ^ lrel) * 8; // swizzled source chunk (u16)

    f32x4 acc[4][4];
    #pragma unroll
    for (int i = 0; i < 4; ++i)
        #pragma unroll
        for (int j = 0; j < 4; ++j)
            acc[i][j] = (f32x4){0.f, 0.f, 0.f, 0.f};

    const int nt = K >> 6;   // K / 64 tiles

    // prologue: stage tile 0 into buffer 0
    #pragma unroll
    for (int j = 0; j < 4; ++j)
        gl_lds16(&A[(i64)(m0 + grow + 8 * j) * lda + gchk],
                 &As[(srow0 + 8 * j) * 64]);
    #pragma unroll
    for (int j = 0; j < 4; ++j)
        gl_lds16(&B[(i64)(n0 + grow + 8 * j) * ldb + gchk],
                 &Bs[(srow0 + 8 * j) * 64]);

    int cur = 0;
    for (int t = 0; t < nt; ++t) {
        const int nxt = cur ^ 1;
        if (t + 1 < nt) {
            const int k0n = (t + 1) << 6;
            #pragma unroll
            for (int j = 0; j < 4; ++j)
                gl_lds16(&A[(i64)(m0 + grow + 8 * j) * lda + k0n + gchk],
                         &As[nxt * 8192 + (srow0 + 8 * j) * 64]);
            #pragma unroll
            for (int j = 0; j < 4; ++j)
                gl_lds16(&B[(i64)(n0 + grow + 8 * j) * ldb + k0n + gchk],
                         &Bs[nxt * 8192 + (srow0 + 8 * j) * 64]);
            // wait only for the OLDEST 8 (current tile); prefetch stays in flight
            asm volatile("s_waitcnt vmcnt(8)" ::: "memory");
        } else {
            asm volatile("s_waitcnt vmcnt(0)" ::: "memory");
        }
        asm volatile("s_barrier" ::: "memory");   // buf[cur] ready on all waves

        const u16* Ab = &As[cur * 8192];
        const u16* Bb = &Bs[cur * 8192];
        __builtin_amdgcn_s_setprio(1);
        #pragma unroll
        for (int kk = 0; kk < 2; ++kk) {
            short8 af[4], bg[4];
            #pragma unroll
            for (int m = 0; m < 4; ++m)
                af[m] = *(const short8*)&Ab[(wr + m * 16 + lrow) * 64 +
                                            (((kk * 32) + kblk * 8) ^ rsw)];
            #pragma unroll
            for (int n = 0; n < 4; ++n)
                bg[n] = *(const short8*)&Bb[(wc + n * 16 + lrow) * 64 +
                                            (((kk * 32) + kblk * 8) ^ rsw)];

            #pragma unroll
            for (int m = 0; m < 4; ++m)
                #pragma unroll
                for (int n = 0; n < 4; ++n)
                    acc[m][n] = __builtin_amdgcn_mfma_f32_16x16x32_bf16(
                        af[m], bg[n], acc[m][n], 0, 0, 0);
        }
        __builtin_amdgcn_s_setprio(0);
        asm volatile("s_barrier" ::: "memory");   // all reads of buf[cur] done
        cur = nxt;
    }

    // epilogue: C/D layout col = lane&15, row = 4*(lane>>4)+reg
    #pragma unroll
    for (int m = 0; m < 4; ++m) {
        #pragma unroll
        for (int n = 0; n < 4; ++n) {
            const int col = n0 + wc + n * 16 + lrow;
            float bv = BIAS ? bias[col] : 0.f;
            #pragma unroll
            for (int r = 0; r < 4; ++r) {
                const int row = m0 + wr + m * 16 + kblk * 4 + r;
                float val = acc[m][n][r] * alpha + bv;
                if (OUTBF)
                    ((u16*)Cv)[coff + (i64)row * ldc + col] = f2bf(val);
                else
                    ((float*)Cv)[coff + (i64)row * ldc + col] = val;
            }
        }
    }
}

// ---------------------------------------------------------------------------
__device__ __forceinline__ float wave_red_sum(float v) {
    #pragma unroll
    for (int o = 32; o > 0; o >>= 1) v += __shfl_down(v, o, 64);
    return v;
}

// ---------------------------------------------------------------------------
// Barrier-free fused masked softmax + renorm + head-mean.
// Wave w handles heads {w, w+4} of one (batch, q-row); full-row reductions
// via 6-step shfl_xor butterflies (no __syncthreads in head loop).
// ---------------------------------------------------------------------------
__global__ __launch_bounds__(256) void softmax_fused_kernel(
    const u16* __restrict__ scores, const int* __restrict__ mask,
    u16* __restrict__ attn_bf, float* __restrict__ amean,
    i64 s_bstride, i64 m_bstride, i64 a_bstride, i64 o_bstride)
{
    const int qrow = blockIdx.x;
    const int bb   = blockIdx.y;
    const u16* sbase = scores + (i64)bb * s_bstride;
    const int* mrow = mask + (i64)bb * m_bstride + (i64)qrow * NL;
    u16* abase = attn_bf + (i64)bb * a_bstride;
    float* orow = amean + (i64)bb * o_bstride + (i64)qrow * NL;

    const int tid  = threadIdx.x;
    const int lane = tid & 63;
    const int wave = tid >> 6;           // 0..3

    __shared__ float wsum[4][NL];        // per-wave head-sum partials

    const int e0 = lane * 8;
    const int e1 = 512 + lane * 8;

    float mv[16];
    {
        i32x4 m0a = *(const i32x4*)&mrow[e0];
        i32x4 m0b = *(const i32x4*)&mrow[e0 + 4];
        i32x4 m1a = *(const i32x4*)&mrow[e1];
        i32x4 m1b = *(const i32x4*)&mrow[e1 + 4];
        #pragma unroll
        for (int i = 0; i < 4; ++i) {
            mv[i]      = (float)m0a[i];
            mv[4 + i]  = (float)m0b[i];
            mv[8 + i]  = (float)m1a[i];
            mv[12 + i] = (float)m1b[i];
        }
    }

    float msum[16];
    #pragma unroll
    for (int i = 0; i < 16; ++i) msum[i] = 0.f;

    #pragma unroll
    for (int hh = 0; hh < 2; ++hh) {
        const int h = wave + hh * 4;
        const u16* srow_p = sbase + ((i64)h * NL + qrow) * NL;
        u16* arow_p = abase + ((i64)h * NL + qrow) * NL;

        u16x8 s0 = *(const u16x8*)&srow_p[e0];
        u16x8 s1 = *(const u16x8*)&srow_p[e1];

        float zv[16];
        float lmax = -1e30f;
        #pragma unroll
        for (int i = 0; i < 8; ++i) {
            zv[i]     = bf2f(s0[i]) * mv[i];
            zv[8 + i] = bf2f(s1[i]) * mv[8 + i];
        }
        #pragma unroll
        for (int i = 0; i < 16; ++i) lmax = fmaxf(lmax, zv[i]);
        #pragma unroll
        for (int o = 1; o < 64; o <<= 1)
            lmax = fmaxf(lmax, __shfl_xor(lmax, o, 64));

        float e[16];
        float ls = 0.f;
        #pragma unroll
        for (int i = 0; i < 16; ++i) { e[i] = __expf(zv[i] - lmax); ls += e[i]; }
        #pragma unroll
        for (int o = 1; o < 64; o <<= 1) ls += __shfl_xor(ls, o, 64);

        float ls2 = 0.f;
        #pragma unroll
        for (int i = 0; i < 16; ++i) { e[i] = e[i] / ls * mv[i]; ls2 += e[i]; }
        #pragma unroll
        for (int o = 1; o < 64; o <<= 1) ls2 += __shfl_xor(ls2, o, 64);

        const float inv = 1.0f / (ls2 + 1e-13f);
        u16x8 o0, o1;
        #pragma unroll
        for (int i = 0; i < 8; ++i) {
            float p0 = e[i] * inv;
            float p1 = e[8 + i] * inv;
            o0[i] = f2bf(p0);
            o1[i] = f2bf(p1);
            msum[i]     += p0;
            msum[8 + i] += p1;
        }
        *(u16x8*)&arow_p[e0] = o0;
        *(u16x8*)&arow_p[e1] = o1;
    }

    #pragma unroll
    for (int i = 0; i < 8; ++i) {
        wsum[wave][e0 + i] = msum[i];
        wsum[wave][e1 + i] = msum[8 + i];
    }
    __syncthreads();
    #pragma unroll
    for (int i = 0; i < 4; ++i) {
        int j = tid + i * 256;
        orow[j] = (wsum[0][j] + wsum[1][j] + wsum[2][j] + wsum[3][j]) * 0.125f;
    }
}

// ---------------------------------------------------------------------------
// FUSED split-K reduce + bias + residual + LayerNorm.
// part: P bf16 partials [P][rows*ND] (pstride elems apart). grid: rows.
// x = sum_p part[p] + bias + resid ; out = LN(x)*gamma + beta.
// 256 threads, 2 elems/thread.
// ---------------------------------------------------------------------------
template <int P>
__global__ __launch_bounds__(256) void ln_fused_kernel(
    const u16* __restrict__ part, const float* __restrict__ bias,
    const float* __restrict__ resid,
    const float* __restrict__ gamma, const float* __restrict__ beta,
    float* __restrict__ out, i64 pstride)
{
    const int row = blockIdx.x;
    const int tid = threadIdx.x;
    const int lane = tid & 63, wid = tid >> 6;
    __shared__ float red[8];

    const i64 base = (i64)row * ND;
    float x0 = bias[tid]       + resid[base + tid];
    float x1 = bias[tid + 256] + resid[base + tid + 256];
    #pragma unroll
    for (int p = 0; p < P; ++p) {
        x0 += bf2f(part[(i64)p * pstride + base + tid]);
        x1 += bf2f(part[(i64)p * pstride + base + tid + 256]);
    }

    float s  = x0 + x1;
    float s2 = x0 * x0 + x1 * x1;
    s  = wave_red_sum(s);
    s2 = wave_red_sum(s2);
    if (lane == 0) { red[wid] = s; red[4 + wid] = s2; }
    __syncthreads();
    const float S  = red[0] + red[1] + red[2] + red[3];
    const float S2 = red[4] + red[5] + red[6] + red[7];
    const float mu  = S * (1.0f / ND);
    const float var = S2 * (1.0f / ND) - mu * mu;
    const float inv = rsqrtf(var + 1e-5f);

    out[base + tid]       = (x0 - mu) * inv * gamma[tid] + beta[tid];
    out[base + tid + 256] = (x1 - mu) * inv * gamma[tid + 256] + beta[tid + 256];
}

// ===========================================================================
// Fallback fp32 path (small workspace): per-(b,h) scalar GEMM pipeline.
// ===========================================================================
template <bool BT, bool BIAS, bool ACC>
__global__ __launch_bounds__(256) void gemm_kernel(
    const float* __restrict__ A, const float* __restrict__ B,
    float* __restrict__ C, const float* __restrict__ bias,
    int M, int N, int K, int lda, int ldb, int ldc, float alpha)
{
    __shared__ float Asf[16][68];
    __shared__ float Bsf[16][68];
    const int tid = threadIdx.x;
    const int tx = tid & 15, ty = tid >> 4;
    const int m0 = blockIdx.y * 64, n0 = blockIdx.x * 64;
    float acc[4][4] = {};

    for (int k0 = 0; k0 < K; k0 += 16) {
        {
            int r = tid >> 2, kq = (tid & 3) << 2;
            float4 a = *reinterpret_cast<const float4*>(&A[(i64)(m0 + r) * lda + k0 + kq]);
            Asf[kq][r] = a.x; Asf[kq + 1][r] = a.y; Asf[kq + 2][r] = a.z; Asf[kq + 3][r] = a.w;
        }
        if (BT) {
            int r = tid >> 2, kq = (tid & 3) << 2;
            float4 b = *reinterpret_cast<const float4*>(&B[(i64)(n0 + r) * ldb + k0 + kq]);
            Bsf[kq][r] = b.x; Bsf[kq + 1][r] = b.y; Bsf[kq + 2][r] = b.z; Bsf[kq + 3][r] = b.w;
        } else {
            int kk = tid >> 4, n4 = (tid & 15) << 2;
            float4 b = *reinterpret_cast<const float4*>(&B[(i64)(k0 + kk) * ldb + n0 + n4]);
            *reinterpret_cast<float4*>(&Bsf[kk][n4]) = b;
        }
        __syncthreads();
        #pragma unroll
        for (int kk = 0; kk < 16; ++kk) {
            float4 a4 = *reinterpret_cast<const float4*>(&Asf[kk][ty << 2]);
            float4 b4 = *reinterpret_cast<const float4*>(&Bsf[kk][tx << 2]);
            float a[4] = {a4.x, a4.y, a4.z, a4.w};
            float b[4] = {b4.x, b4.y, b4.z, b4.w};
            #pragma unroll
            for (int i = 0; i < 4; ++i)
                #pragma unroll
                for (int j = 0; j < 4; ++j)
                    acc[i][j] = fmaf(a[i], b[j], acc[i][j]);
        }
        __syncthreads();
    }
    #pragma unroll
    for (int i = 0; i < 4; ++i) {
        int m = m0 + (ty << 2) + i;
        #pragma unroll
        for (int j = 0; j < 4; ++j) {
            int n = n0 + (tx << 2) + j;
            float val = acc[i][j] * alpha;
            if (BIAS) val += bias[n];
            i64 idx = (i64)m * ldc + n;
            if (ACC) C[idx] += val; else C[idx] = val;
        }
    }
}

__device__ __forceinline__ float wave_red_max(float v) {
    #pragma unroll
    for (int o = 32; o > 0; o >>= 1) v = fmaxf(v, __shfl_down(v, o, 64));
    return v;
}

__global__ __launch_bounds__(256) void softmax_kernel(
    float* __restrict__ attn, const int* __restrict__ mask)
{
    const int qrow = blockIdx.x;
    float* row = attn + (i64)qrow * NL;
    const int* mrow = mask + (i64)qrow * NL;
    const int tid = threadIdx.x;
    const int lane = tid & 63, wid = tid >> 6;
    __shared__ float red[4];

    float zv[4], mv[4];
    float lmax = -1e30f;
    #pragma unroll
    for (int i = 0; i < 4; ++i) {
        mv[i] = (float)mrow[tid + i * 256];
        zv[i] = row[tid + i * 256] * mv[i];
        lmax  = fmaxf(lmax, zv[i]);
    }
    float wv = wave_red_max(lmax);
    if (lane == 0) red[wid] = wv;
    __syncthreads();
    const float gmax = fmaxf(fmaxf(red[0], red[1]), fmaxf(red[2], red[3]));
    float e[4]; float ls = 0.f;
    #pragma unroll
    for (int i = 0; i < 4; ++i) { e[i] = __expf(zv[i] - gmax); ls += e[i]; }
    __syncthreads();
    wv = wave_red_sum(ls);
    if (lane == 0) red[wid] = wv;
    __syncthreads();
    const float S1 = red[0] + red[1] + red[2] + red[3];
    float ls2 = 0.f;
    #pragma unroll
    for (int i = 0; i < 4; ++i) { e[i] = e[i] / S1 * mv[i]; ls2 += e[i]; }
    __syncthreads();
    wv = wave_red_sum(ls2);
    if (lane == 0) red[wid] = wv;
    __syncthreads();
    const float S2 = red[0] + red[1] + red[2] + red[3];
    const float inv = 1.0f / (S2 + 1e-13f);
    #pragma unroll
    for (int i = 0; i < 4; ++i) row[tid + i * 256] = e[i] * inv;
}

__global__ __launch_bounds__(256) void mean_acc_kernel(
    const float* __restrict__ attn, float* __restrict__ out, int first)
{
    i64 idx = (i64)blockIdx.x * 256 + threadIdx.x;
    float v = attn[idx] * 0.125f;
    out[idx] = first ? v : (out[idx] + v);
}

__global__ __launch_bounds__(256) void ln_kernel(
    const float* __restrict__ fcout, const float* __restrict__ resid,
    const float* __restrict__ gamma, const float* __restrict__ beta,
    float* __restrict__ out)
{
    const int row = blockIdx.x;
    const float* xr = fcout + (i64)row * ND;
    const float* rr = resid + (i64)row * ND;
    const int tid = threadIdx.x;
    const int lane = tid & 63, wid = tid >> 6;
    __shared__ float red[8];

    float x0 = xr[tid] + rr[tid];
    float x1 = xr[tid + 256] + rr[tid + 256];
    float s  = x0 + x1;
    float s2 = x0 * x0 + x1 * x1;
    s  = wave_red_sum(s);
    s2 = wave_red_sum(s2);
    if (lane == 0) { red[wid] = s; red[4 + wid] = s2; }
    __syncthreads();
    const float S  = red[0] + red[1] + red[2] + red[3];
    const float S2 = red[4] + red[5] + red[6] + red[7];
    const float mu  = S * (1.0f / ND);
    const float var = S2 * (1.0f / ND) - mu * mu;
    const float inv = rsqrtf(var + 1e-5f);

    out[(i64)row * ND + tid]       = (x0 - mu) * inv * gamma[tid] + beta[tid];
    out[(i64)row * ND + tid + 256] = (x1 - mu) * inv * gamma[tid + 256] + beta[tid + 256];
}

// ---------------------------------------------------------------------------
extern "C" void kernel_launch(void* const* d_in, const int* in_sizes, int n_in,
                              void* d_out, int out_size, void* d_ws, size_t ws_size,
                              hipStream_t stream)
{
    const float* q     = (const float*)d_in[0];
    const int*   mask  = (const int*)  d_in[1];
    const float* k     = (const float*)d_in[2];
    const float* v     = (const float*)d_in[3];
    const float* Wq    = (const float*)d_in[4];
    const float* Wk    = (const float*)d_in[5];
    const float* Wv    = (const float*)d_in[6];
    const float* Wfc   = (const float*)d_in[7];
    const float* bfc   = (const float*)d_in[8];
    const float* gamma = (const float*)d_in[9];
    const float* beta  = (const float*)d_in[10];

    float* out       = (float*)d_out;                 // [B,L,D]
    float* attn_mean = out + (i64)NB * NL * ND;       // [B,L,L]

    const float inv_sqrt_d = 0.04419417382415922f;    // 1/sqrt(512)
    const i64 LD  = (i64)NL * ND;                     // 524288
    const i64 LL  = (i64)NL * NL;                     // 1048576
    const i64 ND2 = (i64)ND * ND;                     // 262144
    const i64 HLD = (i64)NH * LD;                     // 4194304
    const i64 HLL = (i64)NH * LL;                     // 8388608
    dim3 blk(256);

    const size_t MB = 1048576;

    if (ws_size >= 196 * MB) {
        // ================= full-batch bf16 MFMA path (~180 MiB) ===============
        char* wsb = (char*)d_ws;
        u16* Wq_bf  = (u16*)(wsb);              // 4 MiB each; Wq/Wk CONTIGUOUS
        u16* Wk_bf  = (u16*)(wsb + 4   * MB);
        u16* Wv_bf  = (u16*)(wsb + 8   * MB);
        u16* Wfc_bf = (u16*)(wsb + 12  * MB);
        u16* q_bf   = (u16*)(wsb + 16  * MB);   // q/k CONTIGUOUS (4 MiB each)
        u16* k_bf   = (u16*)(wsb + 20  * MB);
        u16* v_bf   = (u16*)(wsb + 24  * MB);
        u16* qh     = (u16*)(wsb + 28  * MB);   // qh/kh CONTIGUOUS (32 MiB each)
        u16* kh     = (u16*)(wsb + 60  * MB);
        u16* vht    = (u16*)(wsb + 92  * MB);   // [B,H,D,L] bf16, 32 MiB
        u16* scores = (u16*)(wsb + 124 * MB);   // [B,H,L,L] bf16, 64 MiB -> 188
        u16* attn_bf  = qh;                      // [B,H,L,L] bf16, over qh+kh
        u16* concat   = (u16*)(wsb + 124 * MB);  // [B*L,H*D] bf16, 32 MiB (scores dead)
        u16* fcpart   = (u16*)(wsb + 156 * MB);  // [4, B*L, 512] bf16, 16 MiB

        // ---- all 7 tensors -> bf16 in ONE launch (each is 2M floats)
        {
            CvtArgs a;
            a.src[0] = Wq;  a.dst[0] = Wq_bf;
            a.src[1] = Wk;  a.dst[1] = Wk_bf;
            a.src[2] = Wv;  a.dst[2] = Wv_bf;
            a.src[3] = Wfc; a.dst[3] = Wfc_bf;
            a.src[4] = q;   a.dst[4] = q_bf;
            a.src[5] = k;   a.dst[5] = k_bf;
            a.src[6] = v;   a.dst[6] = v_bf;
            a.src[7] = v;   a.dst[7] = v_bf;   // unused (y<7)
            cvt_multi_kernel<<<dim3(1024, 7), blk, 0, stream>>>(a, 262144);
        }

        // ---- fused Q+K projections: z = sel*32 + b*8 + h (64)
        mfma_gemm<true, false><<<dim3(4, 8, 64), blk, 0, stream>>>(
            q_bf, Wq_bf, qh, nullptr, ND, ND, ND, ND, 1.0f,
            4 * LD, LD, 0,   8 * ND2, 0, ND2,   4 * HLD, HLD, LD);
        // V projection (operands swapped): vht[b,h,e,l] = Wv[h,e,:] . v[b,l,:]
        mfma_gemm<true, false><<<dim3(8, 4, 32), blk, 0, stream>>>(
            Wv_bf, v_bf, vht, nullptr, ND, ND, ND, NL, 1.0f,
            0, 0, ND2,   0, LD, 0,   0, HLD, LD);

        // ---- scores[b,h,q,k] = (1/sqrt(D)) qh . kh  -> bf16
        mfma_gemm<true, false><<<dim3(8, 8, 32), blk, 0, stream>>>(
            qh, kh, scores, nullptr, ND, ND, ND, NL, inv_sqrt_d,
            0, HLD, LD,   0, HLD, LD,   0, HLL, LL);

        // ---- softmax + renorm + bf16 attn + head-mean (all batches)
        softmax_fused_kernel<<<dim3(NL, NB), blk, 0, stream>>>(
            scores, mask, attn_bf, attn_mean, HLL, LL, HLL, LL);

        // ---- PV: concat[b*L+l, h*512+e] = sum_k attn[b,h,l,k] vht[b,h,e,k]
        mfma_gemm<true, false><<<dim3(4, 8, 32), blk, 0, stream>>>(
            attn_bf, vht, concat, nullptr, NL, NL, NL, NH * ND, 1.0f,
            0, HLL, LL,   0, HLD, LD,   0, (i64)NL * NH * ND, (i64)ND);

        // ---- fc split-K: z = K-chunk (4 x 1024), bf16 partials
        mfma_gemm<true, false><<<dim3(4, 32, 4), blk, 0, stream>>>(
            concat, Wfc_bf, fcpart, nullptr, NL, NH * ND, NH * ND, ND, 1.0f,
            0, 0, NL,   0, 0, NL,   0, 0, (i64)NB * NL * ND);

        // ---- fused reduce + bias + residual + LayerNorm (all batches)
        ln_fused_kernel<4><<<dim3(NB * NL), blk, 0, stream>>>(
            fcpart, bfc, q, gamma, beta, out, (i64)NB * NL * ND);

    } else if (ws_size >= 64 * MB) {
        // ================= per-batch bf16 MFMA path (~55 MiB) ================
        char* wsb = (char*)d_ws;
        u16* Wq_bf  = (u16*)(wsb);
        u16* Wk_bf  = (u16*)(wsb + 4  * MB);
        u16* Wv_bf  = (u16*)(wsb + 8  * MB);
        u16* Wfc_bf = (u16*)(wsb + 12 * MB);
        u16* qb_bf  = (u16*)(wsb + 16 * MB);
        u16* kb_bf  = (u16*)(wsb + 17 * MB);
        u16* vb_bf  = (u16*)(wsb + 18 * MB);
        u16* qh     = (u16*)(wsb + 19 * MB);   // 8 MiB
        u16* kh     = (u16*)(wsb + 27 * MB);   // 8 MiB
        u16* vht    = (u16*)(wsb + 35 * MB);   // 8 MiB
        u16* scores = (u16*)(wsb + 43 * MB);   // [H,L,L] bf16, 16 MiB
        u16* attn_bf  = qh;                    // 16 MiB over qh+kh
        u16* concat   = (u16*)(wsb + 43 * MB); // 8 MiB (scores dead)
        u16* fcpart   = (u16*)(wsb + 51 * MB); // [4,L,512] bf16, 4 MiB

        {
            CvtArgs a;
            a.src[0] = Wq;  a.dst[0] = Wq_bf;
            a.src[1] = Wk;  a.dst[1] = Wk_bf;
            a.src[2] = Wv;  a.dst[2] = Wv_bf;
            a.src[3] = Wfc; a.dst[3] = Wfc_bf;
            a.src[4] = Wq;  a.dst[4] = Wq_bf;  // unused
            a.src[5] = Wq;  a.dst[5] = Wq_bf;
            a.src[6] = Wq;  a.dst[6] = Wq_bf;
            a.src[7] = Wq;  a.dst[7] = Wq_bf;
            cvt_multi_kernel<<<dim3(1024, 4), blk, 0, stream>>>(a, 262144);
        }

        for (int b = 0; b < NB; ++b) {
            const float* qb = q + (i64)b * LD;
            const float* kb = k + (i64)b * LD;
            const float* vb = v + (i64)b * LD;
            const int* maskb = mask + (i64)b * LL;

            {
                CvtArgs a;
                a.src[0] = qb; a.dst[0] = qb_bf;
                a.src[1] = kb; a.dst[1] = kb_bf;
                a.src[2] = vb; a.dst[2] = vb_bf;
                a.src[3] = vb; a.dst[3] = vb_bf;
                a.src[4] = vb; a.dst[4] = vb_bf;
                a.src[5] = vb; a.dst[5] = vb_bf;
                a.src[6] = vb; a.dst[6] = vb_bf;
                a.src[7] = vb; a.dst[7] = vb_bf;
                cvt_multi_kernel<<<dim3(256, 3), blk, 0, stream>>>(a, 65536);
            }

            mfma_gemm<true, false><<<dim3(4, 8, NH), blk, 0, stream>>>(
                qb_bf, Wq_bf, qh, nullptr, ND, ND, ND, ND, 1.0f,
                0, 0, 0,   0, 0, ND2,   0, 0, LD);
            mfma_gemm<true, false><<<dim3(4, 8, NH), blk, 0, stream>>>(
                kb_bf, Wk_bf, kh, nullptr, ND, ND, ND, ND, 1.0f,
                0, 0, 0,   0, 0, ND2,   0, 0, LD);
            mfma_gemm<true, false><<<dim3(8, 4, NH), blk, 0, stream>>>(
                Wv_bf, vb_bf, vht, nullptr, ND, ND, ND, NL, 1.0f,
                0, 0, ND2,   0, 0, 0,   0, 0, LD);

            mfma_gemm<true, false><<<dim3(8, 8, NH), blk, 0, stream>>>(
                qh, kh, scores, nullptr, ND, ND, ND, NL, inv_sqrt_d,
                0, 0, LD,   0, 0, LD,   0, 0, LL);

            softmax_fused_kernel<<<dim3(NL, 1), blk, 0, stream>>>(
                scores, maskb, attn_bf, attn_mean + (i64)b * LL, 0, 0, 0, 0);

            mfma_gemm<true, false><<<dim3(4, 8, NH), blk, 0, stream>>>(
                attn_bf, vht, concat, nullptr, NL, NL, NL, NH * ND, 1.0f,
                0, 0, LL,   0, 0, LD,   0, 0, (i64)ND);

            mfma_gemm<true, false><<<dim3(4, 8, 4), blk, 0, stream>>>(
                concat, Wfc_bf, fcpart, nullptr, NL, NH * ND, NH * ND, ND, 1.0f,
                0, 0, NL,   0, 0, NL,   0, 0, LD);
            ln_fused_kernel<4><<<dim3(NL), blk, 0, stream>>>(
                fcpart, bfc, qb, gamma, beta, out + (i64)b * LD, LD);
        }
    } else {
        // ======================= fp32 fallback (12 MiB) =======================
        float* ws = (float*)d_ws;
        float* qh_h   = ws;
        float* kh_h   = ws + LD;
        float* vh_h   = ws + 2 * LD;
        float* attn_h = ws + 3 * LD;
        float* headout = qh_h;
        float* fcout   = ws + 5 * LD;

        for (int b = 0; b < NB; ++b) {
            const float* qb = q + (i64)b * LD;
            const float* kb = k + (i64)b * LD;
            const float* vb = v + (i64)b * LD;
            const int* maskb = mask + (i64)b * LL;

            for (int h = 0; h < NH; ++h) {
                const i64 wofs = (i64)h * ND2;
                gemm_kernel<true, false, false><<<dim3(8, 16, 1), blk, 0, stream>>>(
                    qb, Wq + wofs, qh_h, nullptr, NL, ND, ND, ND, ND, ND, 1.0f);
                gemm_kernel<true, false, false><<<dim3(8, 16, 1), blk, 0, stream>>>(
                    kb, Wk + wofs, kh_h, nullptr, NL, ND, ND, ND, ND, ND, 1.0f);
                gemm_kernel<true, false, false><<<dim3(8, 16, 1), blk, 0, stream>>>(
                    vb, Wv + wofs, vh_h, nullptr, NL, ND, ND, ND, ND, ND, 1.0f);
                gemm_kernel<true, false, false><<<dim3(16, 16, 1), blk, 0, stream>>>(
                    qh_h, kh_h, attn_h, nullptr, NL, NL, ND, ND, ND, NL, inv_sqrt_d);
                softmax_kernel<<<dim3(NL), blk, 0, stream>>>(attn_h, maskb);
                mean_acc_kernel<<<dim3(4096), blk, 0, stream>>>(
                    attn_h, attn_mean + (i64)b * LL, h == 0 ? 1 : 0);
                gemm_kernel<false, false, false><<<dim3(8, 16, 1), blk, 0, stream>>>(
                    attn_h, vh_h, headout, nullptr, NL, ND, NL, NL, ND, ND, 1.0f);
                if (h == 0)
                    gemm_kernel<true, true, false><<<dim3(8, 16, 1), blk, 0, stream>>>(
                        headout, Wfc + (i64)h * ND, fcout, bfc, NL, ND, ND, ND, NH * ND, ND, 1.0f);
                else
                    gemm_kernel<true, false, true><<<dim3(8, 16, 1), blk, 0, stream>>>(
                        headout, Wfc + (i64)h * ND, fcout, nullptr, NL, ND, ND, ND, NH * ND, ND, 1.0f);
            }
            ln_kernel<<<dim3(NL), blk, 0, stream>>>(fcout, qb, gamma, beta, out + (i64)b * LD);
        }
    }
}

// Round 19
// 247.915 us; speedup vs baseline: 1.1418x; 1.0109x over previous
//
#include <hip/hip_runtime.h>
#include <hip/hip_bf16.h>
#include <cmath>

typedef long long i64;
typedef unsigned short u16;
typedef __attribute__((ext_vector_type(8))) short short8;
typedef __attribute__((ext_vector_type(8))) unsigned short u16x8;
typedef __attribute__((ext_vector_type(4))) float f32x4;
typedef __attribute__((ext_vector_type(4))) int i32x4;

#define NB 4
#define NL 1024
#define ND 512
#define NH 8

__device__ __forceinline__ u16 f2bf(float f) {
    __hip_bfloat16 h = __float2bfloat16(f);
    return __builtin_bit_cast(unsigned short, h);
}
__device__ __forceinline__ float bf2f(u16 u) {
    return __builtin_bit_cast(float, (unsigned)u << 16);
}

// async global->LDS, 16B per lane. LDS dest is wave-uniform base + lane*16.
typedef __attribute__((address_space(3))) u16* lds_u16p;
typedef const __attribute__((address_space(1))) u16* glb_u16p;
__device__ __forceinline__ void gl_lds16(const u16* g, u16* l) {
    __builtin_amdgcn_global_load_lds((glb_u16p)g, (lds_u16p)l, 16, 0, 0);
}

// ---------------------------------------------------------------------------
// fused fp32 -> bf16 convert for up to 8 tensors (blockIdx.y selects)
// ---------------------------------------------------------------------------
struct CvtArgs {
    const float* src[8];
    u16* dst[8];
};

__global__ __launch_bounds__(256) void cvt_multi_kernel(CvtArgs args, int n8)
{
    int i = blockIdx.x * 256 + threadIdx.x;
    if (i >= n8) return;
    const float* __restrict__ src = args.src[blockIdx.y];
    u16* __restrict__ dst = args.dst[blockIdx.y];
    float4 a = ((const float4*)src)[2 * i];
    float4 b = ((const float4*)src)[2 * i + 1];
    u16x8 o;
    o[0] = f2bf(a.x); o[1] = f2bf(a.y); o[2] = f2bf(a.z); o[3] = f2bf(a.w);
    o[4] = f2bf(b.x); o[5] = f2bf(b.y); o[6] = f2bf(b.z); o[7] = f2bf(b.w);
    *(u16x8*)&dst[8 * i] = o;
}

// ---------------------------------------------------------------------------
// bf16 MFMA GEMM, BT-form:  C[m,n] = alpha * sum_k A[m,k]*B[n,k]  (+ bias[n])
// A: [M,K] bf16 (lda), B: [N,K] bf16 (ldb), C: fp32 or bf16 (OUTBF, ldc).
// z-offsets (3 levels): off = (z>>5)*s0 + ((z>>3)&3)*s1 + (z&7)*s2.
// m97 geometry, BK=64, XOR-swizzled LDS (T2), XCD-chunked block swizzle (T1),
// T3/T4 pipeline: double-buffered LDS, raw s_barrier, counted vmcnt(8),
// T5 setprio(1) around the MFMA cluster.
// M,N multiples of 128; K multiple of 64; lda/ldb multiples of 8.
// ---------------------------------------------------------------------------
template <bool OUTBF, bool BIAS>
__global__ __launch_bounds__(256) void mfma_gemm(
    const u16* __restrict__ A, const u16* __restrict__ B,
    void* __restrict__ Cv, const float* __restrict__ bias,
    int K, int lda, int ldb, int ldc, float alpha,
    i64 a_s0, i64 a_s1, i64 a_s2,
    i64 b_s0, i64 b_s1, i64 b_s2,
    i64 c_s0, i64 c_s1, i64 c_s2)
{
    // ---- XCD-chunked swizzle: contiguous work chunk per XCD (L2 locality)
    const int gxy  = gridDim.x * gridDim.y;
    const int nblk = gxy * gridDim.z;
    const int lin  = blockIdx.x + gridDim.x * blockIdx.y + gxy * blockIdx.z;
    const int swz  = (lin & 7) * (nblk >> 3) + (lin >> 3);
    const int bz   = swz / gxy;
    const int rxy  = swz - bz * gxy;
    const int by   = rxy / gridDim.x;
    const int bx   = rxy - by * gridDim.x;

    const int zq = bz >> 5, zh = (bz >> 3) & 3, zl = bz & 7;
    A += (i64)zq * a_s0 + (i64)zh * a_s1 + (i64)zl * a_s2;
    B += (i64)zq * b_s0 + (i64)zh * b_s1 + (i64)zl * b_s2;
    const i64 coff = (i64)zq * c_s0 + (i64)zh * c_s1 + (i64)zl * c_s2;

    __shared__ alignas(16) u16 As[2 * 128 * 64];   // double buffer
    __shared__ alignas(16) u16 Bs[2 * 128 * 64];

    const int tid  = threadIdx.x;
    const int lane = tid & 63;
    const int wave = tid >> 6;           // 0..3
    const int wr   = (wave >> 1) * 64;   // wave row offset: 0,64
    const int wc   = (wave & 1) * 64;    // wave col offset: 0,64
    const int lrow = lane & 15;
    const int kblk = lane >> 4;          // 0..3
    const int rsw  = (lrow & 7) * 8;     // read-side XOR (u16 units)
    const int m0   = by * 128;
    const int n0   = bx * 128;

    // staging: wave w stages rows [32w,32w+32); 4 issues of 8 rows for A, B.
    // lane l -> rel row (l>>3), SWIZZLED source chunk ((l&7) ^ (l>>3)).
    const int srow0 = wave * 32;
    const int lrel  = lane >> 3;               // 0..7
    const int grow  = srow0 + lrel;
    const int gchk  = ((lane & 7) ^ lrel) * 8; // swizzled source chunk (u16)

    f32x4 acc[4][4];
    #pragma unroll
    for (int i = 0; i < 4; ++i)
        #pragma unroll
        for (int j = 0; j < 4; ++j)
            acc[i][j] = (f32x4){0.f, 0.f, 0.f, 0.f};

    const int nt = K >> 6;   // K / 64 tiles

    // prologue: stage tile 0 into buffer 0
    #pragma unroll
    for (int j = 0; j < 4; ++j)
        gl_lds16(&A[(i64)(m0 + grow + 8 * j) * lda + gchk],
                 &As[(srow0 + 8 * j) * 64]);
    #pragma unroll
    for (int j = 0; j < 4; ++j)
        gl_lds16(&B[(i64)(n0 + grow + 8 * j) * ldb + gchk],
                 &Bs[(srow0 + 8 * j) * 64]);

    int cur = 0;
    for (int t = 0; t < nt; ++t) {
        const int nxt = cur ^ 1;
        if (t + 1 < nt) {
            const int k0n = (t + 1) << 6;
            #pragma unroll
            for (int j = 0; j < 4; ++j)
                gl_lds16(&A[(i64)(m0 + grow + 8 * j) * lda + k0n + gchk],
                         &As[nxt * 8192 + (srow0 + 8 * j) * 64]);
            #pragma unroll
            for (int j = 0; j < 4; ++j)
                gl_lds16(&B[(i64)(n0 + grow + 8 * j) * ldb + k0n + gchk],
                         &Bs[nxt * 8192 + (srow0 + 8 * j) * 64]);
            // wait only for the OLDEST 8 (current tile); prefetch stays in flight
            asm volatile("s_waitcnt vmcnt(8)" ::: "memory");
        } else {
            asm volatile("s_waitcnt vmcnt(0)" ::: "memory");
        }
        asm volatile("s_barrier" ::: "memory");   // buf[cur] ready on all waves

        const u16* Ab = &As[cur * 8192];
        const u16* Bb = &Bs[cur * 8192];
        __builtin_amdgcn_s_setprio(1);
        #pragma unroll
        for (int kk = 0; kk < 2; ++kk) {
            short8 af[4], bg[4];
            #pragma unroll
            for (int m = 0; m < 4; ++m)
                af[m] = *(const short8*)&Ab[(wr + m * 16 + lrow) * 64 +
                                            (((kk * 32) + kblk * 8) ^ rsw)];
            #pragma unroll
            for (int n = 0; n < 4; ++n)
                bg[n] = *(const short8*)&Bb[(wc + n * 16 + lrow) * 64 +
                                            (((kk * 32) + kblk * 8) ^ rsw)];

            #pragma unroll
            for (int m = 0; m < 4; ++m)
                #pragma unroll
                for (int n = 0; n < 4; ++n)
                    acc[m][n] = __builtin_amdgcn_mfma_f32_16x16x32_bf16(
                        af[m], bg[n], acc[m][n], 0, 0, 0);
        }
        __builtin_amdgcn_s_setprio(0);
        asm volatile("s_barrier" ::: "memory");   // all reads of buf[cur] done
        cur = nxt;
    }

    // epilogue: C/D layout col = lane&15, row = 4*(lane>>4)+reg
    #pragma unroll
    for (int m = 0; m < 4; ++m) {
        #pragma unroll
        for (int n = 0; n < 4; ++n) {
            const int col = n0 + wc + n * 16 + lrow;
            float bv = BIAS ? bias[col] : 0.f;
            #pragma unroll
            for (int r = 0; r < 4; ++r) {
                const int row = m0 + wr + m * 16 + kblk * 4 + r;
                float val = acc[m][n][r] * alpha + bv;
                if (OUTBF)
                    ((u16*)Cv)[coff + (i64)row * ldc + col] = f2bf(val);
                else
                    ((float*)Cv)[coff + (i64)row * ldc + col] = val;
            }
        }
    }
}

// ---------------------------------------------------------------------------
__device__ __forceinline__ float wave_red_sum(float v) {
    #pragma unroll
    for (int o = 32; o > 0; o >>= 1) v += __shfl_down(v, o, 64);
    return v;
}

// ---------------------------------------------------------------------------
// Barrier-free fused masked softmax + renorm + head-mean.
// Wave w handles heads {w, w+4} of one (batch, q-row); full-row reductions
// via 6-step shfl_xor butterflies (no __syncthreads in head loop).
// ---------------------------------------------------------------------------
__global__ __launch_bounds__(256) void softmax_fused_kernel(
    const u16* __restrict__ scores, const int* __restrict__ mask,
    u16* __restrict__ attn_bf, float* __restrict__ amean,
    i64 s_bstride, i64 m_bstride, i64 a_bstride, i64 o_bstride)
{
    const int qrow = blockIdx.x;
    const int bb   = blockIdx.y;
    const u16* sbase = scores + (i64)bb * s_bstride;
    const int* mrow = mask + (i64)bb * m_bstride + (i64)qrow * NL;
    u16* abase = attn_bf + (i64)bb * a_bstride;
    float* orow = amean + (i64)bb * o_bstride + (i64)qrow * NL;

    const int tid  = threadIdx.x;
    const int lane = tid & 63;
    const int wave = tid >> 6;           // 0..3

    __shared__ float wsum[4][NL];        // per-wave head-sum partials

    const int e0 = lane * 8;
    const int e1 = 512 + lane * 8;

    float mv[16];
    {
        i32x4 m0a = *(const i32x4*)&mrow[e0];
        i32x4 m0b = *(const i32x4*)&mrow[e0 + 4];
        i32x4 m1a = *(const i32x4*)&mrow[e1];
        i32x4 m1b = *(const i32x4*)&mrow[e1 + 4];
        #pragma unroll
        for (int i = 0; i < 4; ++i) {
            mv[i]      = (float)m0a[i];
            mv[4 + i]  = (float)m0b[i];
            mv[8 + i]  = (float)m1a[i];
            mv[12 + i] = (float)m1b[i];
        }
    }

    float msum[16];
    #pragma unroll
    for (int i = 0; i < 16; ++i) msum[i] = 0.f;

    #pragma unroll
    for (int hh = 0; hh < 2; ++hh) {
        const int h = wave + hh * 4;
        const u16* srow_p = sbase + ((i64)h * NL + qrow) * NL;
        u16* arow_p = abase + ((i64)h * NL + qrow) * NL;

        u16x8 s0 = *(const u16x8*)&srow_p[e0];
        u16x8 s1 = *(const u16x8*)&srow_p[e1];

        float zv[16];
        float lmax = -1e30f;
        #pragma unroll
        for (int i = 0; i < 8; ++i) {
            zv[i]     = bf2f(s0[i]) * mv[i];
            zv[8 + i] = bf2f(s1[i]) * mv[8 + i];
        }
        #pragma unroll
        for (int i = 0; i < 16; ++i) lmax = fmaxf(lmax, zv[i]);
        #pragma unroll
        for (int o = 1; o < 64; o <<= 1)
            lmax = fmaxf(lmax, __shfl_xor(lmax, o, 64));

        float e[16];
        float ls = 0.f;
        #pragma unroll
        for (int i = 0; i < 16; ++i) { e[i] = __expf(zv[i] - lmax); ls += e[i]; }
        #pragma unroll
        for (int o = 1; o < 64; o <<= 1) ls += __shfl_xor(ls, o, 64);

        float ls2 = 0.f;
        #pragma unroll
        for (int i = 0; i < 16; ++i) { e[i] = e[i] / ls * mv[i]; ls2 += e[i]; }
        #pragma unroll
        for (int o = 1; o < 64; o <<= 1) ls2 += __shfl_xor(ls2, o, 64);

        const float inv = 1.0f / (ls2 + 1e-13f);
        u16x8 o0, o1;
        #pragma unroll
        for (int i = 0; i < 8; ++i) {
            float p0 = e[i] * inv;
            float p1 = e[8 + i] * inv;
            o0[i] = f2bf(p0);
            o1[i] = f2bf(p1);
            msum[i]     += p0;
            msum[8 + i] += p1;
        }
        *(u16x8*)&arow_p[e0] = o0;
        *(u16x8*)&arow_p[e1] = o1;
    }

    #pragma unroll
    for (int i = 0; i < 8; ++i) {
        wsum[wave][e0 + i] = msum[i];
        wsum[wave][e1 + i] = msum[8 + i];
    }
    __syncthreads();
    #pragma unroll
    for (int i = 0; i < 4; ++i) {
        int j = tid + i * 256;
        orow[j] = (wsum[0][j] + wsum[1][j] + wsum[2][j] + wsum[3][j]) * 0.125f;
    }
}

// ---------------------------------------------------------------------------
// FUSED split-K reduce + bias + residual + LayerNorm.
// part: P bf16 partials [P][rows*ND] (pstride elems apart). grid: rows.
// ---------------------------------------------------------------------------
template <int P>
__global__ __launch_bounds__(256) void ln_fused_kernel(
    const u16* __restrict__ part, const float* __restrict__ bias,
    const float* __restrict__ resid,
    const float* __restrict__ gamma, const float* __restrict__ beta,
    float* __restrict__ out, i64 pstride)
{
    const int row = blockIdx.x;
    const int tid = threadIdx.x;
    const int lane = tid & 63, wid = tid >> 6;
    __shared__ float red[8];

    const i64 base = (i64)row * ND;
    float x0 = bias[tid]       + resid[base + tid];
    float x1 = bias[tid + 256] + resid[base + tid + 256];
    #pragma unroll
    for (int p = 0; p < P; ++p) {
        x0 += bf2f(part[(i64)p * pstride + base + tid]);
        x1 += bf2f(part[(i64)p * pstride + base + tid + 256]);
    }

    float s  = x0 + x1;
    float s2 = x0 * x0 + x1 * x1;
    s  = wave_red_sum(s);
    s2 = wave_red_sum(s2);
    if (lane == 0) { red[wid] = s; red[4 + wid] = s2; }
    __syncthreads();
    const float S  = red[0] + red[1] + red[2] + red[3];
    const float S2 = red[4] + red[5] + red[6] + red[7];
    const float mu  = S * (1.0f / ND);
    const float var = S2 * (1.0f / ND) - mu * mu;
    const float inv = rsqrtf(var + 1e-5f);

    out[base + tid]       = (x0 - mu) * inv * gamma[tid] + beta[tid];
    out[base + tid + 256] = (x1 - mu) * inv * gamma[tid + 256] + beta[tid + 256];
}

// ===========================================================================
// Fallback fp32 path (small workspace): per-(b,h) scalar GEMM pipeline.
// ===========================================================================
template <bool BT, bool BIAS, bool ACC>
__global__ __launch_bounds__(256) void gemm_kernel(
    const float* __restrict__ A, const float* __restrict__ B,
    float* __restrict__ C, const float* __restrict__ bias,
    int M, int N, int K, int lda, int ldb, int ldc, float alpha)
{
    __shared__ float Asf[16][68];
    __shared__ float Bsf[16][68];
    const int tid = threadIdx.x;
    const int tx = tid & 15, ty = tid >> 4;
    const int m0 = blockIdx.y * 64, n0 = blockIdx.x * 64;
    float acc[4][4] = {};

    for (int k0 = 0; k0 < K; k0 += 16) {
        {
            int r = tid >> 2, kq = (tid & 3) << 2;
            float4 a = *reinterpret_cast<const float4*>(&A[(i64)(m0 + r) * lda + k0 + kq]);
            Asf[kq][r] = a.x; Asf[kq + 1][r] = a.y; Asf[kq + 2][r] = a.z; Asf[kq + 3][r] = a.w;
        }
        if (BT) {
            int r = tid >> 2, kq = (tid & 3) << 2;
            float4 b = *reinterpret_cast<const float4*>(&B[(i64)(n0 + r) * ldb + k0 + kq]);
            Bsf[kq][r] = b.x; Bsf[kq + 1][r] = b.y; Bsf[kq + 2][r] = b.z; Bsf[kq + 3][r] = b.w;
        } else {
            int kk = tid >> 4, n4 = (tid & 15) << 2;
            float4 b = *reinterpret_cast<const float4*>(&B[(i64)(k0 + kk) * ldb + n0 + n4]);
            *reinterpret_cast<float4*>(&Bsf[kk][n4]) = b;
        }
        __syncthreads();
        #pragma unroll
        for (int kk = 0; kk < 16; ++kk) {
            float4 a4 = *reinterpret_cast<const float4*>(&Asf[kk][ty << 2]);
            float4 b4 = *reinterpret_cast<const float4*>(&Bsf[kk][tx << 2]);
            float a[4] = {a4.x, a4.y, a4.z, a4.w};
            float b[4] = {b4.x, b4.y, b4.z, b4.w};
            #pragma unroll
            for (int i = 0; i < 4; ++i)
                #pragma unroll
                for (int j = 0; j < 4; ++j)
                    acc[i][j] = fmaf(a[i], b[j], acc[i][j]);
        }
        __syncthreads();
    }
    #pragma unroll
    for (int i = 0; i < 4; ++i) {
        int m = m0 + (ty << 2) + i;
        #pragma unroll
        for (int j = 0; j < 4; ++j) {
            int n = n0 + (tx << 2) + j;
            float val = acc[i][j] * alpha;
            if (BIAS) val += bias[n];
            i64 idx = (i64)m * ldc + n;
            if (ACC) C[idx] += val; else C[idx] = val;
        }
    }
}

__device__ __forceinline__ float wave_red_max(float v) {
    #pragma unroll
    for (int o = 32; o > 0; o >>= 1) v = fmaxf(v, __shfl_down(v, o, 64));
    return v;
}

__global__ __launch_bounds__(256) void softmax_kernel(
    float* __restrict__ attn, const int* __restrict__ mask)
{
    const int qrow = blockIdx.x;
    float* row = attn + (i64)qrow * NL;
    const int* mrow = mask + (i64)qrow * NL;
    const int tid = threadIdx.x;
    const int lane = tid & 63, wid = tid >> 6;
    __shared__ float red[4];

    float zv[4], mv[4];
    float lmax = -1e30f;
    #pragma unroll
    for (int i = 0; i < 4; ++i) {
        mv[i] = (float)mrow[tid + i * 256];
        zv[i] = row[tid + i * 256] * mv[i];
        lmax  = fmaxf(lmax, zv[i]);
    }
    float wv = wave_red_max(lmax);
    if (lane == 0) red[wid] = wv;
    __syncthreads();
    const float gmax = fmaxf(fmaxf(red[0], red[1]), fmaxf(red[2], red[3]));
    float e[4]; float ls = 0.f;
    #pragma unroll
    for (int i = 0; i < 4; ++i) { e[i] = __expf(zv[i] - gmax); ls += e[i]; }
    __syncthreads();
    wv = wave_red_sum(ls);
    if (lane == 0) red[wid] = wv;
    __syncthreads();
    const float S1 = red[0] + red[1] + red[2] + red[3];
    float ls2 = 0.f;
    #pragma unroll
    for (int i = 0; i < 4; ++i) { e[i] = e[i] / S1 * mv[i]; ls2 += e[i]; }
    __syncthreads();
    wv = wave_red_sum(ls2);
    if (lane == 0) red[wid] = wv;
    __syncthreads();
    const float S2 = red[0] + red[1] + red[2] + red[3];
    const float inv = 1.0f / (S2 + 1e-13f);
    #pragma unroll
    for (int i = 0; i < 4; ++i) row[tid + i * 256] = e[i] * inv;
}

__global__ __launch_bounds__(256) void mean_acc_kernel(
    const float* __restrict__ attn, float* __restrict__ out, int first)
{
    i64 idx = (i64)blockIdx.x * 256 + threadIdx.x;
    float v = attn[idx] * 0.125f;
    out[idx] = first ? v : (out[idx] + v);
}

__global__ __launch_bounds__(256) void ln_kernel(
    const float* __restrict__ fcout, const float* __restrict__ resid,
    const float* __restrict__ gamma, const float* __restrict__ beta,
    float* __restrict__ out)
{
    const int row = blockIdx.x;
    const float* xr = fcout + (i64)row * ND;
    const float* rr = resid + (i64)row * ND;
    const int tid = threadIdx.x;
    const int lane = tid & 63, wid = tid >> 6;
    __shared__ float red[8];

    float x0 = xr[tid] + rr[tid];
    float x1 = xr[tid + 256] + rr[tid + 256];
    float s  = x0 + x1;
    float s2 = x0 * x0 + x1 * x1;
    s  = wave_red_sum(s);
    s2 = wave_red_sum(s2);
    if (lane == 0) { red[wid] = s; red[4 + wid] = s2; }
    __syncthreads();
    const float S  = red[0] + red[1] + red[2] + red[3];
    const float S2 = red[4] + red[5] + red[6] + red[7];
    const float mu  = S * (1.0f / ND);
    const float var = S2 * (1.0f / ND) - mu * mu;
    const float inv = rsqrtf(var + 1e-5f);

    out[(i64)row * ND + tid]       = (x0 - mu) * inv * gamma[tid] + beta[tid];
    out[(i64)row * ND + tid + 256] = (x1 - mu) * inv * gamma[tid + 256] + beta[tid + 256];
}

// ---------------------------------------------------------------------------
extern "C" void kernel_launch(void* const* d_in, const int* in_sizes, int n_in,
                              void* d_out, int out_size, void* d_ws, size_t ws_size,
                              hipStream_t stream)
{
    const float* q     = (const float*)d_in[0];
    const int*   mask  = (const int*)  d_in[1];
    const float* k     = (const float*)d_in[2];
    const float* v     = (const float*)d_in[3];
    const float* Wq    = (const float*)d_in[4];
    const float* Wk    = (const float*)d_in[5];
    const float* Wv    = (const float*)d_in[6];
    const float* Wfc   = (const float*)d_in[7];
    const float* bfc   = (const float*)d_in[8];
    const float* gamma = (const float*)d_in[9];
    const float* beta  = (const float*)d_in[10];

    float* out       = (float*)d_out;                 // [B,L,D]
    float* attn_mean = out + (i64)NB * NL * ND;       // [B,L,L]

    const float inv_sqrt_d = 0.04419417382415922f;    // 1/sqrt(512)
    const i64 LD  = (i64)NL * ND;                     // 524288
    const i64 LL  = (i64)NL * NL;                     // 1048576
    const i64 ND2 = (i64)ND * ND;                     // 262144
    const i64 HLD = (i64)NH * LD;                     // 4194304
    const i64 HLL = (i64)NH * LL;                     // 8388608
    dim3 blk(256);

    const size_t MB = 1048576;

    if (ws_size >= 196 * MB) {
        // ================= full-batch bf16 MFMA path (~180 MiB) ===============
        char* wsb = (char*)d_ws;
        u16* Wq_bf  = (u16*)(wsb);              // 4 MiB each; Wq/Wk CONTIGUOUS
        u16* Wk_bf  = (u16*)(wsb + 4   * MB);
        u16* Wv_bf  = (u16*)(wsb + 8   * MB);
        u16* Wfc_bf = (u16*)(wsb + 12  * MB);
        u16* q_bf   = (u16*)(wsb + 16  * MB);   // q/k CONTIGUOUS (4 MiB each)
        u16* k_bf   = (u16*)(wsb + 20  * MB);
        u16* v_bf   = (u16*)(wsb + 24  * MB);
        u16* qh     = (u16*)(wsb + 28  * MB);   // qh/kh CONTIGUOUS (32 MiB each)
        u16* kh     = (u16*)(wsb + 60  * MB);
        u16* vht    = (u16*)(wsb + 92  * MB);   // [B,H,D,L] bf16, 32 MiB
        u16* scores = (u16*)(wsb + 124 * MB);   // [B,H,L,L] bf16, 64 MiB -> 188
        u16* attn_bf  = qh;                      // [B,H,L,L] bf16, over qh+kh
        u16* concat   = (u16*)(wsb + 124 * MB);  // [B*L,H*D] bf16, 32 MiB (scores dead)
        u16* fcpart   = (u16*)(wsb + 156 * MB);  // [4, B*L, 512] bf16, 16 MiB

        // ---- all 7 tensors -> bf16 in ONE launch (each is 2M floats)
        {
            CvtArgs a;
            a.src[0] = Wq;  a.dst[0] = Wq_bf;
            a.src[1] = Wk;  a.dst[1] = Wk_bf;
            a.src[2] = Wv;  a.dst[2] = Wv_bf;
            a.src[3] = Wfc; a.dst[3] = Wfc_bf;
            a.src[4] = q;   a.dst[4] = q_bf;
            a.src[5] = k;   a.dst[5] = k_bf;
            a.src[6] = v;   a.dst[6] = v_bf;
            a.src[7] = v;   a.dst[7] = v_bf;   // unused (y<7)
            cvt_multi_kernel<<<dim3(1024, 7), blk, 0, stream>>>(a, 262144);
        }

        // ---- fused Q+K projections: z = sel*32 + b*8 + h (64)
        mfma_gemm<true, false><<<dim3(4, 8, 64), blk, 0, stream>>>(
            q_bf, Wq_bf, qh, nullptr, ND, ND, ND, ND, 1.0f,
            4 * LD, LD, 0,   8 * ND2, 0, ND2,   4 * HLD, HLD, LD);
        // V projection (operands swapped): vht[b,h,e,l] = Wv[h,e,:] . v[b,l,:]
        mfma_gemm<true, false><<<dim3(8, 4, 32), blk, 0, stream>>>(
            Wv_bf, v_bf, vht, nullptr, ND, ND, ND, NL, 1.0f,
            0, 0, ND2,   0, LD, 0,   0, HLD, LD);

        // ---- scores[b,h,q,k] = (1/sqrt(D)) qh . kh  -> bf16
        mfma_gemm<true, false><<<dim3(8, 8, 32), blk, 0, stream>>>(
            qh, kh, scores, nullptr, ND, ND, ND, NL, inv_sqrt_d,
            0, HLD, LD,   0, HLD, LD,   0, HLL, LL);

        // ---- softmax + renorm + bf16 attn + head-mean (all batches)
        softmax_fused_kernel<<<dim3(NL, NB), blk, 0, stream>>>(
            scores, mask, attn_bf, attn_mean, HLL, LL, HLL, LL);

        // ---- PV: concat[b*L+l, h*512+e] = sum_k attn[b,h,l,k] vht[b,h,e,k]
        mfma_gemm<true, false><<<dim3(4, 8, 32), blk, 0, stream>>>(
            attn_bf, vht, concat, nullptr, NL, NL, NL, NH * ND, 1.0f,
            0, HLL, LL,   0, HLD, LD,   0, (i64)NL * NH * ND, (i64)ND);

        // ---- fc split-K: z = K-chunk (4 x 1024), bf16 partials
        mfma_gemm<true, false><<<dim3(4, 32, 4), blk, 0, stream>>>(
            concat, Wfc_bf, fcpart, nullptr, NL, NH * ND, NH * ND, ND, 1.0f,
            0, 0, NL,   0, 0, NL,   0, 0, (i64)NB * NL * ND);

        // ---- fused reduce + bias + residual + LayerNorm (all batches)
        ln_fused_kernel<4><<<dim3(NB * NL), blk, 0, stream>>>(
            fcpart, bfc, q, gamma, beta, out, (i64)NB * NL * ND);

    } else if (ws_size >= 64 * MB) {
        // ================= per-batch bf16 MFMA path (~55 MiB) ================
        char* wsb = (char*)d_ws;
        u16* Wq_bf  = (u16*)(wsb);
        u16* Wk_bf  = (u16*)(wsb + 4  * MB);
        u16* Wv_bf  = (u16*)(wsb + 8  * MB);
        u16* Wfc_bf = (u16*)(wsb + 12 * MB);
        u16* qb_bf  = (u16*)(wsb + 16 * MB);
        u16* kb_bf  = (u16*)(wsb + 17 * MB);
        u16* vb_bf  = (u16*)(wsb + 18 * MB);
        u16* qh     = (u16*)(wsb + 19 * MB);   // 8 MiB
        u16* kh     = (u16*)(wsb + 27 * MB);   // 8 MiB
        u16* vht    = (u16*)(wsb + 35 * MB);   // 8 MiB
        u16* scores = (u16*)(wsb + 43 * MB);   // [H,L,L] bf16, 16 MiB
        u16* attn_bf  = qh;                    // 16 MiB over qh+kh
        u16* concat   = (u16*)(wsb + 43 * MB); // 8 MiB (scores dead)
        u16* fcpart   = (u16*)(wsb + 51 * MB); // [4,L,512] bf16, 4 MiB

        {
            CvtArgs a;
            a.src[0] = Wq;  a.dst[0] = Wq_bf;
            a.src[1] = Wk;  a.dst[1] = Wk_bf;
            a.src[2] = Wv;  a.dst[2] = Wv_bf;
            a.src[3] = Wfc; a.dst[3] = Wfc_bf;
            a.src[4] = Wq;  a.dst[4] = Wq_bf;  // unused
            a.src[5] = Wq;  a.dst[5] = Wq_bf;
            a.src[6] = Wq;  a.dst[6] = Wq_bf;
            a.src[7] = Wq;  a.dst[7] = Wq_bf;
            cvt_multi_kernel<<<dim3(1024, 4), blk, 0, stream>>>(a, 262144);
        }

        for (int b = 0; b < NB; ++b) {
            const float* qb = q + (i64)b * LD;
            const float* kb = k + (i64)b * LD;
            const float* vb = v + (i64)b * LD;
            const int* maskb = mask + (i64)b * LL;

            {
                CvtArgs a;
                a.src[0] = qb; a.dst[0] = qb_bf;
                a.src[1] = kb; a.dst[1] = kb_bf;
                a.src[2] = vb; a.dst[2] = vb_bf;
                a.src[3] = vb; a.dst[3] = vb_bf;
                a.src[4] = vb; a.dst[4] = vb_bf;
                a.src[5] = vb; a.dst[5] = vb_bf;
                a.src[6] = vb; a.dst[6] = vb_bf;
                a.src[7] = vb; a.dst[7] = vb_bf;
                cvt_multi_kernel<<<dim3(256, 3), blk, 0, stream>>>(a, 65536);
            }

            mfma_gemm<true, false><<<dim3(4, 8, NH), blk, 0, stream>>>(
                qb_bf, Wq_bf, qh, nullptr, ND, ND, ND, ND, 1.0f,
                0, 0, 0,   0, 0, ND2,   0, 0, LD);
            mfma_gemm<true, false><<<dim3(4, 8, NH), blk, 0, stream>>>(
                kb_bf, Wk_bf, kh, nullptr, ND, ND, ND, ND, 1.0f,
                0, 0, 0,   0, 0, ND2,   0, 0, LD);
            mfma_gemm<true, false><<<dim3(8, 4, NH), blk, 0, stream>>>(
                Wv_bf, vb_bf, vht, nullptr, ND, ND, ND, NL, 1.0f,
                0, 0, ND2,   0, 0, 0,   0, 0, LD);

            mfma_gemm<true, false><<<dim3(8, 8, NH), blk, 0, stream>>>(
                qh, kh, scores, nullptr, ND, ND, ND, NL, inv_sqrt_d,
                0, 0, LD,   0, 0, LD,   0, 0, LL);

            softmax_fused_kernel<<<dim3(NL, 1), blk, 0, stream>>>(
                scores, maskb, attn_bf, attn_mean + (i64)b * LL, 0, 0, 0, 0);

            mfma_gemm<true, false><<<dim3(4, 8, NH), blk, 0, stream>>>(
                attn_bf, vht, concat, nullptr, NL, NL, NL, NH * ND, 1.0f,
                0, 0, LL,   0, 0, LD,   0, 0, (i64)ND);

            mfma_gemm<true, false><<<dim3(4, 8, 4), blk, 0, stream>>>(
                concat, Wfc_bf, fcpart, nullptr, NL, NH * ND, NH * ND, ND, 1.0f,
                0, 0, NL,   0, 0, NL,   0, 0, LD);
            ln_fused_kernel<4><<<dim3(NL), blk, 0, stream>>>(
                fcpart, bfc, qb, gamma, beta, out + (i64)b * LD, LD);
        }
    } else {
        // ======================= fp32 fallback (12 MiB) =======================
        float* ws = (float*)d_ws;
        float* qh_h   = ws;
        float* kh_h   = ws + LD;
        float* vh_h   = ws + 2 * LD;
        float* attn_h = ws + 3 * LD;
        float* headout = qh_h;
        float* fcout   = ws + 5 * LD;

        for (int b = 0; b < NB; ++b) {
            const float* qb = q + (i64)b * LD;
            const float* kb = k + (i64)b * LD;
            const float* vb = v + (i64)b * LD;
            const int* maskb = mask + (i64)b * LL;

            for (int h = 0; h < NH; ++h) {
                const i64 wofs = (i64)h * ND2;
                gemm_kernel<true, false, false><<<dim3(8, 16, 1), blk, 0, stream>>>(
                    qb, Wq + wofs, qh_h, nullptr, NL, ND, ND, ND, ND, ND, 1.0f);
                gemm_kernel<true, false, false><<<dim3(8, 16, 1), blk, 0, stream>>>(
                    kb, Wk + wofs, kh_h, nullptr, NL, ND, ND, ND, ND, ND, 1.0f);
                gemm_kernel<true, false, false><<<dim3(8, 16, 1), blk, 0, stream>>>(
                    vb, Wv + wofs, vh_h, nullptr, NL, ND, ND, ND, ND, ND, 1.0f);
                gemm_kernel<true, false, false><<<dim3(16, 16, 1), blk, 0, stream>>>(
                    qh_h, kh_h, attn_h, nullptr, NL, NL, ND, ND, ND, NL, inv_sqrt_d);
                softmax_kernel<<<dim3(NL), blk, 0, stream>>>(attn_h, maskb);
                mean_acc_kernel<<<dim3(4096), blk, 0, stream>>>(
                    attn_h, attn_mean + (i64)b * LL, h == 0 ? 1 : 0);
                gemm_kernel<false, false, false><<<dim3(8, 16, 1), blk, 0, stream>>>(
                    attn_h, vh_h, headout, nullptr, NL, ND, NL, NL, ND, ND, 1.0f);
                if (h == 0)
                    gemm_kernel<true, true, false><<<dim3(8, 16, 1), blk, 0, stream>>>(
                        headout, Wfc + (i64)h * ND, fcout, bfc, NL, ND, ND, ND, NH * ND, ND, 1.0f);
                else
                    gemm_kernel<true, false, true><<<dim3(8, 16, 1), blk, 0, stream>>>(
                        headout, Wfc + (i64)h * ND, fcout, nullptr, NL, ND, ND, ND, NH * ND, ND, 1.0f);
            }
            ln_kernel<<<dim3(NL), blk, 0, stream>>>(fcout, qb, gamma, beta, out + (i64)b * LD);
        }
    }
}